// Round 2
// baseline (765.172 us; speedup 1.0000x reference)
//
#include <hip/hip_runtime.h>
#include <hip/hip_bf16.h>
#include <math.h>

#define D 128
#define NT 3
#define KTOT (D * (NT + 1))   // 512

// ---------------- zero workspace ----------------
__global__ void zero_kernel(float* __restrict__ p, long long n4) {
    long long i = (long long)blockIdx.x * blockDim.x + threadIdx.x;
    long long stride = (long long)gridDim.x * blockDim.x;
    float4 z = make_float4(0.f, 0.f, 0.f, 0.f);
    for (; i < n4; i += stride) ((float4*)p)[i] = z;
}

// ---------------- prep: softmax(attention), fold into W_cat & biases ----------------
__global__ void prep_kernel(const float* __restrict__ W_edge, const float* __restrict__ b_edge,
                            const float* __restrict__ W_self, const float* __restrict__ b_self,
                            const float* __restrict__ attention,
                            float* __restrict__ wcat, float* __restrict__ biasb) {
    float a0 = attention[0], a1 = attention[1], a2 = attention[2], a3 = attention[3];
    float m = fmaxf(fmaxf(a0, a1), fmaxf(a2, a3));
    float e0 = expf(a0 - m), e1 = expf(a1 - m), e2 = expf(a2 - m), e3 = expf(a3 - m);
    float inv = 1.f / (e0 + e1 + e2 + e3);
    float at[4] = {e0 * inv, e1 * inv, e2 * inv, e3 * inv};

    int idx0 = blockIdx.x * blockDim.x + threadIdx.x;
    int stride = gridDim.x * blockDim.x;
    // wcat[k][j]: rows 0..127 self (at3*W_self), rows 128.. : type t
    for (int i = idx0; i < KTOT * D; i += stride) {
        int k = i >> 7, j = i & (D - 1);
        float v;
        if (k < D) {
            v = at[NT] * W_self[k * D + j];
        } else {
            int t = (k - D) >> 7;
            int kk = (k - D) & (D - 1);
            v = at[t] * W_edge[(t * D + kk) * D + j];
        }
        wcat[i] = v;
    }
    // biasb: [0,384) = at[t]*b_edge[t][j]; [384,512) = at[3]*b_self[j]
    for (int i = idx0; i < KTOT; i += stride) {
        if (i < NT * D) {
            int t = i >> 7, j = i & (D - 1);
            biasb[i] = at[t] * b_edge[t * D + j];
        } else {
            biasb[i] = at[NT] * b_self[i - NT * D];
        }
    }
}

// ================= PATH A: full agg (N x 3 x D) =================
__global__ __launch_bounds__(256) void scatterA_kernel(
    const float* __restrict__ x, const int* __restrict__ ei,
    const int* __restrict__ et, const float* __restrict__ ew,
    float* __restrict__ agg, float* __restrict__ s, int nE) {
    int gtid = blockIdx.x * blockDim.x + threadIdx.x;
    int wave = gtid >> 6;
    int lane = threadIdx.x & 63;
    int nw = (gridDim.x * blockDim.x) >> 6;
    for (int e = wave; e < nE; e += nw) {
        int src = ei[e];
        int dst = ei[nE + e];
        int t = et[e];
        float w = ew[e];
        float2 xv = *(const float2*)(x + (size_t)src * D + lane * 2);
        float* p = agg + (size_t)dst * (NT * D) + t * D + lane * 2;
        unsafeAtomicAdd(p, w * xv.x);
        unsafeAtomicAdd(p + 1, w * xv.y);
        if (lane == 0) unsafeAtomicAdd(s + (size_t)dst * NT + t, w);
    }
}

#define BM 64
#define BK 32
__global__ __launch_bounds__(256) void gemm_gelu_kernel(
    const float* __restrict__ x, const float* __restrict__ agg,
    const float* __restrict__ s, const float* __restrict__ wcat,
    const float* __restrict__ biasb, float* __restrict__ out, int nNodes) {
    __shared__ float As[BK][BM + 1];
    __shared__ float Bs[BK][D];

    int tx = threadIdx.x;
    int row0 = blockIdx.x * BM;
    int cg = tx & 31;
    int rg = tx >> 5;
    int lr = tx >> 3;
    int lc = (tx & 7) * 4;

    float acc[8][4];
#pragma unroll
    for (int i = 0; i < 8; ++i)
#pragma unroll
        for (int j = 0; j < 4; ++j) acc[i][j] = 0.f;

    for (int k0 = 0; k0 < KTOT; k0 += BK) {
        const float* srcBase;
        int strideA, koff;
        if (k0 < D) { srcBase = x; strideA = D; koff = k0; }
        else        { srcBase = agg; strideA = NT * D; koff = k0 - D; }
#pragma unroll
        for (int h = 0; h < 2; ++h) {
            int r = lr + h * 32;
            int node = row0 + r;
            if (node >= nNodes) node = nNodes - 1;
            float4 v = *(const float4*)(srcBase + (size_t)node * strideA + koff + lc);
            As[lc + 0][r] = v.x; As[lc + 1][r] = v.y;
            As[lc + 2][r] = v.z; As[lc + 3][r] = v.w;
        }
        {
            int br = tx >> 5;
            int bc = (tx & 31) * 4;
#pragma unroll
            for (int h = 0; h < 4; ++h) {
                int r = br + h * 8;
                *(float4*)(&Bs[r][bc]) = *(const float4*)(wcat + (size_t)(k0 + r) * D + bc);
            }
        }
        __syncthreads();
#pragma unroll
        for (int kk = 0; kk < BK; ++kk) {
            float4 b = *(const float4*)(&Bs[kk][cg * 4]);
            float a[8];
            *(float4*)(a)     = *(const float4*)(&As[kk][rg * 8]);
            *(float4*)(a + 4) = *(const float4*)(&As[kk][rg * 8 + 4]);
#pragma unroll
            for (int i = 0; i < 8; ++i) {
                acc[i][0] = fmaf(a[i], b.x, acc[i][0]);
                acc[i][1] = fmaf(a[i], b.y, acc[i][1]);
                acc[i][2] = fmaf(a[i], b.z, acc[i][2]);
                acc[i][3] = fmaf(a[i], b.w, acc[i][3]);
            }
        }
        __syncthreads();
    }

    int jc = cg * 4;
    float4 bb0 = *(const float4*)(biasb + 0 * D + jc);
    float4 bb1 = *(const float4*)(biasb + 1 * D + jc);
    float4 bb2 = *(const float4*)(biasb + 2 * D + jc);
    float4 bsv = *(const float4*)(biasb + NT * D + jc);
#pragma unroll
    for (int i = 0; i < 8; ++i) {
        int node = row0 + rg * 8 + i;
        if (node >= nNodes) break;
        float s0 = s[(size_t)node * NT + 0];
        float s1 = s[(size_t)node * NT + 1];
        float s2 = s[(size_t)node * NT + 2];
        float4 r;
        r.x = acc[i][0] + bsv.x + s0 * bb0.x + s1 * bb1.x + s2 * bb2.x;
        r.y = acc[i][1] + bsv.y + s0 * bb0.y + s1 * bb1.y + s2 * bb2.y;
        r.z = acc[i][2] + bsv.z + s0 * bb0.z + s1 * bb1.z + s2 * bb2.z;
        r.w = acc[i][3] + bsv.w + s0 * bb0.w + s1 * bb1.w + s2 * bb2.w;
        const float kInvSqrt2 = 0.70710678118654752440f;
        r.x = 0.5f * r.x * (1.f + erff(r.x * kInvSqrt2));
        r.y = 0.5f * r.y * (1.f + erff(r.y * kInvSqrt2));
        r.z = 0.5f * r.z * (1.f + erff(r.z * kInvSqrt2));
        r.w = 0.5f * r.w * (1.f + erff(r.w * kInvSqrt2));
        *(float4*)(out + (size_t)node * D + jc) = r;
    }
}

// ================= PATH B: one N x D buffer, per-type passes =================
__global__ __launch_bounds__(256) void scatterB_kernel(
    const float* __restrict__ x, const int* __restrict__ ei,
    const int* __restrict__ et, const float* __restrict__ ew,
    float* __restrict__ buf, float* __restrict__ s, int nE, int ttgt) {
    int gtid = blockIdx.x * blockDim.x + threadIdx.x;
    int wave = gtid >> 6;
    int lane = threadIdx.x & 63;
    int nw = (gridDim.x * blockDim.x) >> 6;
    for (int e = wave; e < nE; e += nw) {
        if (et[e] != ttgt) continue;
        int src = ei[e];
        int dst = ei[nE + e];
        float w = ew[e];
        float2 xv = *(const float2*)(x + (size_t)src * D + lane * 2);
        float* p = buf + (size_t)dst * D + lane * 2;
        unsafeAtomicAdd(p, w * xv.x);
        unsafeAtomicAdd(p + 1, w * xv.y);
        if (lane == 0) unsafeAtomicAdd(s + (size_t)dst * NT + ttgt, w);
    }
}

template <bool FIRST>
__global__ __launch_bounds__(256) void gemm128_kernel(
    const float* __restrict__ A, const float* __restrict__ wc,
    const float* __restrict__ bias, float* __restrict__ out, int nNodes) {
    __shared__ float As[BK][BM + 1];
    __shared__ float Bs[BK][D];
    int tx = threadIdx.x;
    int row0 = blockIdx.x * BM;
    int cg = tx & 31;
    int rg = tx >> 5;
    int lr = tx >> 3;
    int lc = (tx & 7) * 4;

    float acc[8][4];
#pragma unroll
    for (int i = 0; i < 8; ++i)
#pragma unroll
        for (int j = 0; j < 4; ++j) acc[i][j] = 0.f;

    for (int k0 = 0; k0 < D; k0 += BK) {
#pragma unroll
        for (int h = 0; h < 2; ++h) {
            int r = lr + h * 32;
            int node = row0 + r;
            if (node >= nNodes) node = nNodes - 1;
            float4 v = *(const float4*)(A + (size_t)node * D + k0 + lc);
            As[lc + 0][r] = v.x; As[lc + 1][r] = v.y;
            As[lc + 2][r] = v.z; As[lc + 3][r] = v.w;
        }
        {
            int br = tx >> 5;
            int bc = (tx & 31) * 4;
#pragma unroll
            for (int h = 0; h < 4; ++h) {
                int r = br + h * 8;
                *(float4*)(&Bs[r][bc]) = *(const float4*)(wc + (size_t)(k0 + r) * D + bc);
            }
        }
        __syncthreads();
#pragma unroll
        for (int kk = 0; kk < BK; ++kk) {
            float4 b = *(const float4*)(&Bs[kk][cg * 4]);
            float a[8];
            *(float4*)(a)     = *(const float4*)(&As[kk][rg * 8]);
            *(float4*)(a + 4) = *(const float4*)(&As[kk][rg * 8 + 4]);
#pragma unroll
            for (int i = 0; i < 8; ++i) {
                acc[i][0] = fmaf(a[i], b.x, acc[i][0]);
                acc[i][1] = fmaf(a[i], b.y, acc[i][1]);
                acc[i][2] = fmaf(a[i], b.z, acc[i][2]);
                acc[i][3] = fmaf(a[i], b.w, acc[i][3]);
            }
        }
        __syncthreads();
    }
    int jc = cg * 4;
#pragma unroll
    for (int i = 0; i < 8; ++i) {
        int node = row0 + rg * 8 + i;
        if (node >= nNodes) break;
        float4 r;
        if (FIRST) {
            float4 bv = *(const float4*)(bias + jc);
            r.x = acc[i][0] + bv.x; r.y = acc[i][1] + bv.y;
            r.z = acc[i][2] + bv.z; r.w = acc[i][3] + bv.w;
        } else {
            float4 o = *(const float4*)(out + (size_t)node * D + jc);
            r.x = acc[i][0] + o.x; r.y = acc[i][1] + o.y;
            r.z = acc[i][2] + o.z; r.w = acc[i][3] + o.w;
        }
        *(float4*)(out + (size_t)node * D + jc) = r;
    }
}

__global__ __launch_bounds__(256) void biasgelu_kernel(
    float* __restrict__ out, const float* __restrict__ s,
    const float* __restrict__ biasb, int nN) {
    int idx = blockIdx.x * blockDim.x + threadIdx.x;
    int total = nN * (D / 4);
    int stride = gridDim.x * blockDim.x;
    const float kInvSqrt2 = 0.70710678118654752440f;
    for (int i = idx; i < total; i += stride) {
        int n = i >> 5;
        int jc = (i & 31) * 4;
        float s0 = s[(size_t)n * NT + 0];
        float s1 = s[(size_t)n * NT + 1];
        float s2 = s[(size_t)n * NT + 2];
        float4 bb0 = *(const float4*)(biasb + 0 * D + jc);
        float4 bb1 = *(const float4*)(biasb + 1 * D + jc);
        float4 bb2 = *(const float4*)(biasb + 2 * D + jc);
        float4 r = *(float4*)(out + (size_t)n * D + jc);
        r.x += s0 * bb0.x + s1 * bb1.x + s2 * bb2.x;
        r.y += s0 * bb0.y + s1 * bb1.y + s2 * bb2.y;
        r.z += s0 * bb0.z + s1 * bb1.z + s2 * bb2.z;
        r.w += s0 * bb0.w + s1 * bb1.w + s2 * bb2.w;
        r.x = 0.5f * r.x * (1.f + erff(r.x * kInvSqrt2));
        r.y = 0.5f * r.y * (1.f + erff(r.y * kInvSqrt2));
        r.z = 0.5f * r.z * (1.f + erff(r.z * kInvSqrt2));
        r.w = 0.5f * r.w * (1.f + erff(r.w * kInvSqrt2));
        *(float4*)(out + (size_t)n * D + jc) = r;
    }
}

// ================= PATH C: zero-workspace fallback =================
__global__ __launch_bounds__(256) void selfmv_kernel(
    const float* __restrict__ x, const float* __restrict__ Ws,
    const float* __restrict__ bs, const float* __restrict__ attn,
    float* __restrict__ out, int nN) {
    float a0 = attn[0], a1 = attn[1], a2 = attn[2], a3 = attn[3];
    float m = fmaxf(fmaxf(a0, a1), fmaxf(a2, a3));
    float e3 = expf(a3 - m);
    float inv = 1.f / (expf(a0 - m) + expf(a1 - m) + expf(a2 - m) + e3);
    float at3 = e3 * inv;
    int wave = (blockIdx.x * blockDim.x + threadIdx.x) >> 6;
    int lane = threadIdx.x & 63;
    int nw = (gridDim.x * blockDim.x) >> 6;
    for (int n = wave; n < nN; n += nw) {
        float2 xr = *(const float2*)(x + (size_t)n * D + lane * 2);
        float acc0 = 0.f, acc1 = 0.f;
#pragma unroll
        for (int k = 0; k < D; ++k) {
            float xv = __shfl((k & 1) ? xr.y : xr.x, k >> 1);
            float2 wv = *(const float2*)(Ws + (size_t)k * D + lane * 2);
            acc0 = fmaf(xv, wv.x, acc0);
            acc1 = fmaf(xv, wv.y, acc1);
        }
        float2 r;
        r.x = at3 * (acc0 + bs[lane * 2]);
        r.y = at3 * (acc1 + bs[lane * 2 + 1]);
        *(float2*)(out + (size_t)n * D + lane * 2) = r;
    }
}

__global__ __launch_bounds__(256) void edgemv_kernel(
    const float* __restrict__ x, const int* __restrict__ ei,
    const int* __restrict__ et, const float* __restrict__ ew,
    const float* __restrict__ We, const float* __restrict__ be,
    const float* __restrict__ attn, float* __restrict__ out, int nE) {
    float a0 = attn[0], a1 = attn[1], a2 = attn[2], a3 = attn[3];
    float m = fmaxf(fmaxf(a0, a1), fmaxf(a2, a3));
    float e0 = expf(a0 - m), e1 = expf(a1 - m), e2 = expf(a2 - m), e3 = expf(a3 - m);
    float inv = 1.f / (e0 + e1 + e2 + e3);
    float at[NT] = {e0 * inv, e1 * inv, e2 * inv};
    int wave = (blockIdx.x * blockDim.x + threadIdx.x) >> 6;
    int lane = threadIdx.x & 63;
    int nw = (gridDim.x * blockDim.x) >> 6;
    for (int e = wave; e < nE; e += nw) {
        int src = ei[e];
        int dst = ei[nE + e];
        int t = et[e];
        float sc = ew[e] * at[t];
        const float* W = We + (size_t)t * D * D;
        float2 xr = *(const float2*)(x + (size_t)src * D + lane * 2);
        float acc0 = 0.f, acc1 = 0.f;
#pragma unroll
        for (int k = 0; k < D; ++k) {
            float xv = __shfl((k & 1) ? xr.y : xr.x, k >> 1);
            float2 wv = *(const float2*)(W + (size_t)k * D + lane * 2);
            acc0 = fmaf(xv, wv.x, acc0);
            acc1 = fmaf(xv, wv.y, acc1);
        }
        float* p = out + (size_t)dst * D + lane * 2;
        unsafeAtomicAdd(p,     sc * (acc0 + be[(size_t)t * D + lane * 2]));
        unsafeAtomicAdd(p + 1, sc * (acc1 + be[(size_t)t * D + lane * 2 + 1]));
    }
}

__global__ void gelu_kernel(float* __restrict__ p, long long n4) {
    long long i = (long long)blockIdx.x * blockDim.x + threadIdx.x;
    long long stride = (long long)gridDim.x * blockDim.x;
    const float kInvSqrt2 = 0.70710678118654752440f;
    for (; i < n4; i += stride) {
        float4 r = ((float4*)p)[i];
        r.x = 0.5f * r.x * (1.f + erff(r.x * kInvSqrt2));
        r.y = 0.5f * r.y * (1.f + erff(r.y * kInvSqrt2));
        r.z = 0.5f * r.z * (1.f + erff(r.z * kInvSqrt2));
        r.w = 0.5f * r.w * (1.f + erff(r.w * kInvSqrt2));
        ((float4*)p)[i] = r;
    }
}

extern "C" void kernel_launch(void* const* d_in, const int* in_sizes, int n_in,
                              void* d_out, int out_size, void* d_ws, size_t ws_size,
                              hipStream_t stream) {
    const float* x = (const float*)d_in[0];
    const int* ei = (const int*)d_in[1];      // int64 in reference -> int32 here
    const int* et = (const int*)d_in[2];
    const float* ew = (const float*)d_in[3];
    const float* W_edge = (const float*)d_in[4];
    const float* b_edge = (const float*)d_in[5];
    const float* W_self = (const float*)d_in[6];
    const float* b_self = (const float*)d_in[7];
    const float* attention = (const float*)d_in[8];
    float* out = (float*)d_out;

    const int nN = in_sizes[0] / D;   // 100000
    const int nE = in_sizes[2];       // 600000

    const size_t needA = ((size_t)nN * (NT * D + NT) + (size_t)KTOT * D + KTOT) * 4;
    const size_t needB = ((size_t)nN * D + (size_t)nN * NT + (size_t)KTOT * D + KTOT) * 4;
    const int nBlocks = (nN + BM - 1) / BM;

    if (ws_size >= needA) {
        float* agg = (float*)d_ws;                       // nN*384
        float* sW = agg + (size_t)nN * NT * D;           // nN*3
        float* wcat = sW + (size_t)nN * NT;              // 512*128
        float* biasb = wcat + (size_t)KTOT * D;          // 512
        long long zeroFloats = (long long)nN * (NT * D + NT);
        hipLaunchKernelGGL(zero_kernel, dim3(2048), dim3(256), 0, stream, agg, (zeroFloats + 3) / 4);
        hipLaunchKernelGGL(prep_kernel, dim3(64), dim3(256), 0, stream,
                           W_edge, b_edge, W_self, b_self, attention, wcat, biasb);
        hipLaunchKernelGGL(scatterA_kernel, dim3(2048), dim3(256), 0, stream,
                           x, ei, et, ew, agg, sW, nE);
        hipLaunchKernelGGL(gemm_gelu_kernel, dim3(nBlocks), dim3(256), 0, stream,
                           x, agg, sW, wcat, biasb, out, nN);
    } else if (ws_size >= needB) {
        float* buf = (float*)d_ws;                       // nN*128
        float* sW = buf + (size_t)nN * D;                // nN*3
        float* wcat = sW + (size_t)nN * NT;              // 512*128
        float* biasb = wcat + (size_t)KTOT * D;          // 512
        hipLaunchKernelGGL(zero_kernel, dim3(512), dim3(256), 0, stream, sW, (long long)(nN * NT + 3) / 4);
        hipLaunchKernelGGL(prep_kernel, dim3(64), dim3(256), 0, stream,
                           W_edge, b_edge, W_self, b_self, attention, wcat, biasb);
        hipLaunchKernelGGL(gemm128_kernel<true>, dim3(nBlocks), dim3(256), 0, stream,
                           x, wcat, biasb + NT * D, out, nN);
        for (int t = 0; t < NT; ++t) {
            hipLaunchKernelGGL(zero_kernel, dim3(2048), dim3(256), 0, stream, buf, (long long)nN * D / 4);
            hipLaunchKernelGGL(scatterB_kernel, dim3(2048), dim3(256), 0, stream,
                               x, ei, et, ew, buf, sW, nE, t);
            hipLaunchKernelGGL(gemm128_kernel<false>, dim3(nBlocks), dim3(256), 0, stream,
                               buf, wcat + (size_t)(D + t * D) * D, (const float*)nullptr, out, nN);
        }
        hipLaunchKernelGGL(biasgelu_kernel, dim3(2048), dim3(256), 0, stream, out, sW, biasb, nN);
    } else {
        hipLaunchKernelGGL(selfmv_kernel, dim3(2048), dim3(256), 0, stream,
                           x, W_self, b_self, attention, out, nN);
        hipLaunchKernelGGL(edgemv_kernel, dim3(2048), dim3(256), 0, stream,
                           x, ei, et, ew, W_edge, b_edge, attention, out, nE);
        hipLaunchKernelGGL(gelu_kernel, dim3(2048), dim3(256), 0, stream,
                           out, (long long)nN * D / 4);
    }
}

// Round 3
// 341.438 us; speedup vs baseline: 2.2410x; 2.2410x over previous
//
#include <hip/hip_runtime.h>
#include <hip/hip_bf16.h>
#include <math.h>

#define D 128
#define NT 3
#define KTOT (D * (NT + 1))   // 512

// ---------------- zero helpers ----------------
__global__ void zero_kernel(float* __restrict__ p, long long n4) {
    long long i = (long long)blockIdx.x * blockDim.x + threadIdx.x;
    long long stride = (long long)gridDim.x * blockDim.x;
    float4 z = make_float4(0.f, 0.f, 0.f, 0.f);
    for (; i < n4; i += stride) ((float4*)p)[i] = z;
}

__global__ void zeroi_kernel(int* __restrict__ p, int n) {
    int i = blockIdx.x * blockDim.x + threadIdx.x;
    int st = gridDim.x * blockDim.x;
    for (; i < n; i += st) p[i] = 0;
}

// ---------------- prep: softmax(attention), fold into W_cat & biases ----------------
__global__ void prep_kernel(const float* __restrict__ W_edge, const float* __restrict__ b_edge,
                            const float* __restrict__ W_self, const float* __restrict__ b_self,
                            const float* __restrict__ attention,
                            float* __restrict__ wcat, float* __restrict__ biasb) {
    float a0 = attention[0], a1 = attention[1], a2 = attention[2], a3 = attention[3];
    float m = fmaxf(fmaxf(a0, a1), fmaxf(a2, a3));
    float e0 = expf(a0 - m), e1 = expf(a1 - m), e2 = expf(a2 - m), e3 = expf(a3 - m);
    float inv = 1.f / (e0 + e1 + e2 + e3);
    float at[4] = {e0 * inv, e1 * inv, e2 * inv, e3 * inv};

    int idx0 = blockIdx.x * blockDim.x + threadIdx.x;
    int stride = gridDim.x * blockDim.x;
    for (int i = idx0; i < KTOT * D; i += stride) {
        int k = i >> 7, j = i & (D - 1);
        float v;
        if (k < D) {
            v = at[NT] * W_self[k * D + j];
        } else {
            int t = (k - D) >> 7;
            int kk = (k - D) & (D - 1);
            v = at[t] * W_edge[(t * D + kk) * D + j];
        }
        wcat[i] = v;
    }
    for (int i = idx0; i < KTOT; i += stride) {
        if (i < NT * D) {
            int t = i >> 7, j = i & (D - 1);
            biasb[i] = at[t] * b_edge[t * D + j];
        } else {
            biasb[i] = at[NT] * b_self[i - NT * D];
        }
    }
}

// ================= GATHER PATH =================
// fill: bucket edges by dst into padded slots
__global__ __launch_bounds__(256) void fill_kernel(
    const int* __restrict__ ei, const int* __restrict__ et, const float* __restrict__ ew,
    int* __restrict__ deg, int2* __restrict__ csr, int* __restrict__ ovfcnt,
    int* __restrict__ ovflist, int nE, int cap) {
    int e = blockIdx.x * blockDim.x + threadIdx.x;
    if (e >= nE) return;
    int dst = ei[nE + e];
    int pos = atomicAdd(deg + dst, 1);
    if (pos < cap) {
        int src = ei[e];
        int t = et[e];
        csr[(size_t)dst * cap + pos] = make_int2(src | (t << 20), __float_as_int(ew[e]));
    } else {
        int o = atomicAdd(ovfcnt, 1);
        ovflist[o] = e;
    }
}

// gather: one wave per node; accumulate all 3 type rows in registers, write agg once
__global__ __launch_bounds__(256) void gather_kernel(
    const float* __restrict__ x, const int2* __restrict__ csr,
    const int* __restrict__ deg, float* __restrict__ agg,
    float* __restrict__ s, int nN, int cap) {
    int wid = (blockIdx.x * blockDim.x + threadIdx.x) >> 6;
    int lane = threadIdx.x & 63;
    if (wid >= nN) return;
    int dg = deg[wid];
    if (dg > cap) dg = cap;
    float a00 = 0.f, a01 = 0.f, a10 = 0.f, a11 = 0.f, a20 = 0.f, a21 = 0.f;
    float sw0 = 0.f, sw1 = 0.f, sw2 = 0.f;
    const int2* c = csr + (size_t)wid * cap;
    for (int i = 0; i < dg; ++i) {
        int2 e = c[i];
        int src = e.x & 0xFFFFF;
        int t = e.x >> 20;
        float w = __int_as_float(e.y);
        float2 xv = *(const float2*)(x + (size_t)src * D + lane * 2);
        float m0 = (t == 0) ? w : 0.f;
        float m1 = (t == 1) ? w : 0.f;
        float m2 = (t == 2) ? w : 0.f;
        a00 = fmaf(m0, xv.x, a00); a01 = fmaf(m0, xv.y, a01);
        a10 = fmaf(m1, xv.x, a10); a11 = fmaf(m1, xv.y, a11);
        a20 = fmaf(m2, xv.x, a20); a21 = fmaf(m2, xv.y, a21);
        sw0 += m0; sw1 += m1; sw2 += m2;
    }
    float* ap = agg + (size_t)wid * (NT * D);
    *(float2*)(ap + 0 * D + lane * 2) = make_float2(a00, a01);
    *(float2*)(ap + 1 * D + lane * 2) = make_float2(a10, a11);
    *(float2*)(ap + 2 * D + lane * 2) = make_float2(a20, a21);
    if (lane < 3) {
        float sv = (lane == 0) ? sw0 : ((lane == 1) ? sw1 : sw2);
        s[(size_t)wid * NT + lane] = sv;
    }
}

// overflow edges (rare): atomic adds on top of gathered agg
__global__ __launch_bounds__(256) void ovf_kernel(
    const float* __restrict__ x, const int* __restrict__ ei, const int* __restrict__ et,
    const float* __restrict__ ew, const int* __restrict__ ovfcnt, const int* __restrict__ ovflist,
    float* __restrict__ agg, float* __restrict__ s, int nE) {
    int cnt = *ovfcnt;
    int wid = (blockIdx.x * blockDim.x + threadIdx.x) >> 6;
    int lane = threadIdx.x & 63;
    int nw = (gridDim.x * blockDim.x) >> 6;
    for (int i = wid; i < cnt; i += nw) {
        int e = ovflist[i];
        int src = ei[e], dst = ei[nE + e], t = et[e];
        float w = ew[e];
        float2 xv = *(const float2*)(x + (size_t)src * D + lane * 2);
        float* p = agg + (size_t)dst * (NT * D) + t * D + lane * 2;
        unsafeAtomicAdd(p, w * xv.x);
        unsafeAtomicAdd(p + 1, w * xv.y);
        if (lane == 0) unsafeAtomicAdd(s + (size_t)dst * NT + t, w);
    }
}

// ================= PATH A fallback: atomic scatter =================
__global__ __launch_bounds__(256) void scatterA_kernel(
    const float* __restrict__ x, const int* __restrict__ ei,
    const int* __restrict__ et, const float* __restrict__ ew,
    float* __restrict__ agg, float* __restrict__ s, int nE) {
    int gtid = blockIdx.x * blockDim.x + threadIdx.x;
    int wave = gtid >> 6;
    int lane = threadIdx.x & 63;
    int nw = (gridDim.x * blockDim.x) >> 6;
    for (int e = wave; e < nE; e += nw) {
        int src = ei[e];
        int dst = ei[nE + e];
        int t = et[e];
        float w = ew[e];
        float2 xv = *(const float2*)(x + (size_t)src * D + lane * 2);
        float* p = agg + (size_t)dst * (NT * D) + t * D + lane * 2;
        unsafeAtomicAdd(p, w * xv.x);
        unsafeAtomicAdd(p + 1, w * xv.y);
        if (lane == 0) unsafeAtomicAdd(s + (size_t)dst * NT + t, w);
    }
}

// ================= shared GEMM + bias + gelu =================
#define BM 64
#define BK 32
__global__ __launch_bounds__(256) void gemm_gelu_kernel(
    const float* __restrict__ x, const float* __restrict__ agg,
    const float* __restrict__ s, const float* __restrict__ wcat,
    const float* __restrict__ biasb, float* __restrict__ out, int nNodes) {
    __shared__ float As[BK][BM + 1];
    __shared__ float Bs[BK][D];

    int tx = threadIdx.x;
    int row0 = blockIdx.x * BM;
    int cg = tx & 31;
    int rg = tx >> 5;
    int lr = tx >> 3;
    int lc = (tx & 7) * 4;

    float acc[8][4];
#pragma unroll
    for (int i = 0; i < 8; ++i)
#pragma unroll
        for (int j = 0; j < 4; ++j) acc[i][j] = 0.f;

    for (int k0 = 0; k0 < KTOT; k0 += BK) {
        const float* srcBase;
        int strideA, koff;
        if (k0 < D) { srcBase = x; strideA = D; koff = k0; }
        else        { srcBase = agg; strideA = NT * D; koff = k0 - D; }
#pragma unroll
        for (int h = 0; h < 2; ++h) {
            int r = lr + h * 32;
            int node = row0 + r;
            if (node >= nNodes) node = nNodes - 1;
            float4 v = *(const float4*)(srcBase + (size_t)node * strideA + koff + lc);
            As[lc + 0][r] = v.x; As[lc + 1][r] = v.y;
            As[lc + 2][r] = v.z; As[lc + 3][r] = v.w;
        }
        {
            int br = tx >> 5;
            int bc = (tx & 31) * 4;
#pragma unroll
            for (int h = 0; h < 4; ++h) {
                int r = br + h * 8;
                *(float4*)(&Bs[r][bc]) = *(const float4*)(wcat + (size_t)(k0 + r) * D + bc);
            }
        }
        __syncthreads();
#pragma unroll
        for (int kk = 0; kk < BK; ++kk) {
            float4 b = *(const float4*)(&Bs[kk][cg * 4]);
            float a[8];
            *(float4*)(a)     = *(const float4*)(&As[kk][rg * 8]);
            *(float4*)(a + 4) = *(const float4*)(&As[kk][rg * 8 + 4]);
#pragma unroll
            for (int i = 0; i < 8; ++i) {
                acc[i][0] = fmaf(a[i], b.x, acc[i][0]);
                acc[i][1] = fmaf(a[i], b.y, acc[i][1]);
                acc[i][2] = fmaf(a[i], b.z, acc[i][2]);
                acc[i][3] = fmaf(a[i], b.w, acc[i][3]);
            }
        }
        __syncthreads();
    }

    int jc = cg * 4;
    float4 bb0 = *(const float4*)(biasb + 0 * D + jc);
    float4 bb1 = *(const float4*)(biasb + 1 * D + jc);
    float4 bb2 = *(const float4*)(biasb + 2 * D + jc);
    float4 bsv = *(const float4*)(biasb + NT * D + jc);
#pragma unroll
    for (int i = 0; i < 8; ++i) {
        int node = row0 + rg * 8 + i;
        if (node >= nNodes) break;
        float s0 = s[(size_t)node * NT + 0];
        float s1 = s[(size_t)node * NT + 1];
        float s2 = s[(size_t)node * NT + 2];
        float4 r;
        r.x = acc[i][0] + bsv.x + s0 * bb0.x + s1 * bb1.x + s2 * bb2.x;
        r.y = acc[i][1] + bsv.y + s0 * bb0.y + s1 * bb1.y + s2 * bb2.y;
        r.z = acc[i][2] + bsv.z + s0 * bb0.z + s1 * bb1.z + s2 * bb2.z;
        r.w = acc[i][3] + bsv.w + s0 * bb0.w + s1 * bb1.w + s2 * bb2.w;
        const float kInvSqrt2 = 0.70710678118654752440f;
        r.x = 0.5f * r.x * (1.f + erff(r.x * kInvSqrt2));
        r.y = 0.5f * r.y * (1.f + erff(r.y * kInvSqrt2));
        r.z = 0.5f * r.z * (1.f + erff(r.z * kInvSqrt2));
        r.w = 0.5f * r.w * (1.f + erff(r.w * kInvSqrt2));
        *(float4*)(out + (size_t)node * D + jc) = r;
    }
}

// ================= PATH C: zero-workspace fallback =================
__global__ __launch_bounds__(256) void selfmv_kernel(
    const float* __restrict__ x, const float* __restrict__ Ws,
    const float* __restrict__ bs, const float* __restrict__ attn,
    float* __restrict__ out, int nN) {
    float a0 = attn[0], a1 = attn[1], a2 = attn[2], a3 = attn[3];
    float m = fmaxf(fmaxf(a0, a1), fmaxf(a2, a3));
    float e3 = expf(a3 - m);
    float inv = 1.f / (expf(a0 - m) + expf(a1 - m) + expf(a2 - m) + e3);
    float at3 = e3 * inv;
    int wave = (blockIdx.x * blockDim.x + threadIdx.x) >> 6;
    int lane = threadIdx.x & 63;
    int nw = (gridDim.x * blockDim.x) >> 6;
    for (int n = wave; n < nN; n += nw) {
        float2 xr = *(const float2*)(x + (size_t)n * D + lane * 2);
        float acc0 = 0.f, acc1 = 0.f;
#pragma unroll
        for (int k = 0; k < D; ++k) {
            float xv = __shfl((k & 1) ? xr.y : xr.x, k >> 1);
            float2 wv = *(const float2*)(Ws + (size_t)k * D + lane * 2);
            acc0 = fmaf(xv, wv.x, acc0);
            acc1 = fmaf(xv, wv.y, acc1);
        }
        float2 r;
        r.x = at3 * (acc0 + bs[lane * 2]);
        r.y = at3 * (acc1 + bs[lane * 2 + 1]);
        *(float2*)(out + (size_t)n * D + lane * 2) = r;
    }
}

__global__ __launch_bounds__(256) void edgemv_kernel(
    const float* __restrict__ x, const int* __restrict__ ei,
    const int* __restrict__ et, const float* __restrict__ ew,
    const float* __restrict__ We, const float* __restrict__ be,
    const float* __restrict__ attn, float* __restrict__ out, int nE) {
    float a0 = attn[0], a1 = attn[1], a2 = attn[2], a3 = attn[3];
    float m = fmaxf(fmaxf(a0, a1), fmaxf(a2, a3));
    float e0 = expf(a0 - m), e1 = expf(a1 - m), e2 = expf(a2 - m), e3 = expf(a3 - m);
    float inv = 1.f / (e0 + e1 + e2 + e3);
    float at[NT] = {e0 * inv, e1 * inv, e2 * inv};
    int wave = (blockIdx.x * blockDim.x + threadIdx.x) >> 6;
    int lane = threadIdx.x & 63;
    int nw = (gridDim.x * blockDim.x) >> 6;
    for (int e = wave; e < nE; e += nw) {
        int src = ei[e];
        int dst = ei[nE + e];
        int t = et[e];
        float sc = ew[e] * at[t];
        const float* W = We + (size_t)t * D * D;
        float2 xr = *(const float2*)(x + (size_t)src * D + lane * 2);
        float acc0 = 0.f, acc1 = 0.f;
#pragma unroll
        for (int k = 0; k < D; ++k) {
            float xv = __shfl((k & 1) ? xr.y : xr.x, k >> 1);
            float2 wv = *(const float2*)(W + (size_t)k * D + lane * 2);
            acc0 = fmaf(xv, wv.x, acc0);
            acc1 = fmaf(xv, wv.y, acc1);
        }
        float* p = out + (size_t)dst * D + lane * 2;
        unsafeAtomicAdd(p,     sc * (acc0 + be[(size_t)t * D + lane * 2]));
        unsafeAtomicAdd(p + 1, sc * (acc1 + be[(size_t)t * D + lane * 2 + 1]));
    }
}

__global__ void gelu_kernel(float* __restrict__ p, long long n4) {
    long long i = (long long)blockIdx.x * blockDim.x + threadIdx.x;
    long long stride = (long long)gridDim.x * blockDim.x;
    const float kInvSqrt2 = 0.70710678118654752440f;
    for (; i < n4; i += stride) {
        float4 r = ((float4*)p)[i];
        r.x = 0.5f * r.x * (1.f + erff(r.x * kInvSqrt2));
        r.y = 0.5f * r.y * (1.f + erff(r.y * kInvSqrt2));
        r.z = 0.5f * r.z * (1.f + erff(r.z * kInvSqrt2));
        r.w = 0.5f * r.w * (1.f + erff(r.w * kInvSqrt2));
        ((float4*)p)[i] = r;
    }
}

extern "C" void kernel_launch(void* const* d_in, const int* in_sizes, int n_in,
                              void* d_out, int out_size, void* d_ws, size_t ws_size,
                              hipStream_t stream) {
    const float* x = (const float*)d_in[0];
    const int* ei = (const int*)d_in[1];      // int64 in reference -> int32 here
    const int* et = (const int*)d_in[2];
    const float* ew = (const float*)d_in[3];
    const float* W_edge = (const float*)d_in[4];
    const float* b_edge = (const float*)d_in[5];
    const float* W_self = (const float*)d_in[6];
    const float* b_self = (const float*)d_in[7];
    const float* attention = (const float*)d_in[8];
    float* out = (float*)d_out;

    const int nN = in_sizes[0] / D;   // 100000
    const int nE = in_sizes[2];       // 600000
    const int nBlocks = (nN + BM - 1) / BM;

    // base floats for agg, s, wcat, biasb
    const size_t baseFloats = (size_t)nN * NT * D + (size_t)nN * NT + (size_t)KTOT * D + KTOT;

    // pick largest CAP that fits
    int cap = 0;
    const int capCand[4] = {32, 24, 16, 12};
    for (int ci = 0; ci < 4; ++ci) {
        int c = capCand[ci];
        size_t ints = (size_t)nN + 2 + (size_t)nE + (size_t)nN * c * 2;
        size_t need = (baseFloats + ints) * 4;
        if (ws_size >= need) { cap = c; break; }
    }

    if (cap > 0) {
        // ---- gather path ----
        float* agg = (float*)d_ws;                        // nN*384
        float* sW = agg + (size_t)nN * NT * D;            // nN*3
        float* wcat = sW + (size_t)nN * NT;               // 512*128
        float* biasb = wcat + (size_t)KTOT * D;           // 512
        int* deg = (int*)(biasb + KTOT);                  // nN
        int* ovfcnt = deg + nN;                           // 2 (padded)
        int* ovflist = ovfcnt + 2;                        // nE
        int2* csr = (int2*)(ovflist + nE);                // nN*cap

        hipLaunchKernelGGL(zeroi_kernel, dim3(128), dim3(256), 0, stream, deg, nN + 2);
        hipLaunchKernelGGL(prep_kernel, dim3(64), dim3(256), 0, stream,
                           W_edge, b_edge, W_self, b_self, attention, wcat, biasb);
        hipLaunchKernelGGL(fill_kernel, dim3((nE + 255) / 256), dim3(256), 0, stream,
                           ei, et, ew, deg, csr, ovfcnt, ovflist, nE, cap);
        hipLaunchKernelGGL(gather_kernel, dim3((nN + 3) / 4), dim3(256), 0, stream,
                           x, csr, deg, agg, sW, nN, cap);
        hipLaunchKernelGGL(ovf_kernel, dim3(64), dim3(256), 0, stream,
                           x, ei, et, ew, ovfcnt, ovflist, agg, sW, nE);
        hipLaunchKernelGGL(gemm_gelu_kernel, dim3(nBlocks), dim3(256), 0, stream,
                           x, agg, sW, wcat, biasb, out, nN);
        return;
    }

    const size_t needA = (baseFloats) * 4;
    if (ws_size >= needA) {
        // ---- atomic scatter fallback ----
        float* agg = (float*)d_ws;
        float* sW = agg + (size_t)nN * NT * D;
        float* wcat = sW + (size_t)nN * NT;
        float* biasb = wcat + (size_t)KTOT * D;
        long long zeroFloats = (long long)nN * (NT * D + NT);
        hipLaunchKernelGGL(zero_kernel, dim3(2048), dim3(256), 0, stream, agg, (zeroFloats + 3) / 4);
        hipLaunchKernelGGL(prep_kernel, dim3(64), dim3(256), 0, stream,
                           W_edge, b_edge, W_self, b_self, attention, wcat, biasb);
        hipLaunchKernelGGL(scatterA_kernel, dim3(2048), dim3(256), 0, stream,
                           x, ei, et, ew, agg, sW, nE);
        hipLaunchKernelGGL(gemm_gelu_kernel, dim3(nBlocks), dim3(256), 0, stream,
                           x, agg, sW, wcat, biasb, out, nN);
    } else {
        // ---- zero-workspace fallback ----
        hipLaunchKernelGGL(selfmv_kernel, dim3(2048), dim3(256), 0, stream,
                           x, W_self, b_self, attention, out, nN);
        hipLaunchKernelGGL(edgemv_kernel, dim3(2048), dim3(256), 0, stream,
                           x, ei, et, ew, W_edge, b_edge, attention, out, nE);
        hipLaunchKernelGGL(gelu_kernel, dim3(2048), dim3(256), 0, stream,
                           out, (long long)nN * D / 4);
    }
}

// Round 4
// 192.167 us; speedup vs baseline: 3.9818x; 1.7768x over previous
//
#include <hip/hip_runtime.h>
#include <hip/hip_bf16.h>
#include <math.h>

#define D 128
#define NT 3
#define KTOT (D * (NT + 1))   // 512

typedef __attribute__((ext_vector_type(8))) __bf16 bf16x8;
typedef __attribute__((ext_vector_type(4))) float f32x4;

__device__ inline unsigned short f2bf(float f) {
    unsigned int u = __float_as_uint(f);
    unsigned int r = (u + 0x7FFFu + ((u >> 16) & 1u)) >> 16;
    return (unsigned short)r;
}
__device__ inline float bf2f(unsigned short h) {
    return __uint_as_float(((unsigned int)h) << 16);
}

// ---------------- zero helpers ----------------
__global__ void zero_kernel(float* __restrict__ p, long long n4) {
    long long i = (long long)blockIdx.x * blockDim.x + threadIdx.x;
    long long stride = (long long)gridDim.x * blockDim.x;
    float4 z = make_float4(0.f, 0.f, 0.f, 0.f);
    for (; i < n4; i += stride) ((float4*)p)[i] = z;
}

__global__ void zeroi_kernel(int* __restrict__ p, int n) {
    int i = blockIdx.x * blockDim.x + threadIdx.x;
    int st = gridDim.x * blockDim.x;
    for (; i < n; i += st) p[i] = 0;
}

// ---------------- prep: softmax(attention); wcat (f32, fallback), biasb, bfrag (bf16 frag-linear) ----------------
__global__ void prep_kernel(const float* __restrict__ W_edge, const float* __restrict__ b_edge,
                            const float* __restrict__ W_self, const float* __restrict__ b_self,
                            const float* __restrict__ attention,
                            float* __restrict__ wcat, float* __restrict__ biasb,
                            unsigned short* __restrict__ bfrag) {
    float a0 = attention[0], a1 = attention[1], a2 = attention[2], a3 = attention[3];
    float m = fmaxf(fmaxf(a0, a1), fmaxf(a2, a3));
    float e0 = expf(a0 - m), e1 = expf(a1 - m), e2 = expf(a2 - m), e3 = expf(a3 - m);
    float inv = 1.f / (e0 + e1 + e2 + e3);
    float at[4] = {e0 * inv, e1 * inv, e2 * inv, e3 * inv};

    int idx0 = blockIdx.x * blockDim.x + threadIdx.x;
    int stride = gridDim.x * blockDim.x;
    // wcat[k][j] (f32) for fallback path
    for (int i = idx0; i < KTOT * D; i += stride) {
        int k = i >> 7, j = i & (D - 1);
        float v;
        if (k < D) {
            v = at[NT] * W_self[k * D + j];
        } else {
            int t = (k - D) >> 7;
            int kk = (k - D) & (D - 1);
            v = at[t] * W_edge[(t * D + kk) * D + j];
        }
        wcat[i] = v;
    }
    for (int i = idx0; i < KTOT; i += stride) {
        if (i < NT * D) {
            int t = i >> 7, j = i & (D - 1);
            biasb[i] = at[t] * b_edge[t * D + j];
        } else {
            biasb[i] = at[NT] * b_self[i - NT * D];
        }
    }
    // bfrag: [(step*8+cf)*64+lane] -> 8 bf16; B[k][col], col=lane&15, k=step*32+(lane>>4)*8+j
    for (int i = idx0; i < 16 * 8 * 64; i += stride) {
        int l = i & 63;
        int cf = (i >> 6) & 7;
        int step = i >> 9;
        int col = cf * 16 + (l & 15);
        int kb = step * 32 + ((l >> 4) * 8);
#pragma unroll
        for (int j = 0; j < 8; ++j) {
            int k = kb + j;
            float v;
            if (k < D) {
                v = at[NT] * W_self[k * D + col];
            } else {
                int t = (k - D) >> 7;
                int kk = (k - D) & (D - 1);
                v = at[t] * W_edge[(t * D + kk) * D + col];
            }
            bfrag[(size_t)i * 8 + j] = f2bf(v);
        }
    }
}

// ---------------- x -> bf16 into ab[:, 0:128] ----------------
__global__ __launch_bounds__(256) void xcvt_kernel(
    const float* __restrict__ x, unsigned short* __restrict__ ab, int nN) {
    int i = blockIdx.x * blockDim.x + threadIdx.x;
    int total = nN * (D / 4);
    int stride = gridDim.x * blockDim.x;
    for (; i < total; i += stride) {
        int n = i >> 5;
        int c4 = (i & 31) * 4;
        float4 v = *(const float4*)(x + (size_t)n * D + c4);
        ushort4 o;
        o.x = f2bf(v.x); o.y = f2bf(v.y); o.z = f2bf(v.z); o.w = f2bf(v.w);
        *(ushort4*)(ab + (size_t)n * 512 + c4) = o;
    }
}

// ---------------- fill: bucket edges by dst ----------------
__global__ __launch_bounds__(256) void fill_kernel(
    const int* __restrict__ ei, const int* __restrict__ et, const float* __restrict__ ew,
    int* __restrict__ deg, int2* __restrict__ csr, int* __restrict__ ovfcnt,
    int* __restrict__ ovflist, int nE, int cap) {
    int e = blockIdx.x * blockDim.x + threadIdx.x;
    if (e >= nE) return;
    int dst = ei[nE + e];
    int pos = atomicAdd(deg + dst, 1);
    if (pos < cap) {
        int src = ei[e];
        int t = et[e];
        csr[(size_t)dst * cap + pos] = make_int2(src | (t << 20), __float_as_int(ew[e]));
    } else {
        int o = atomicAdd(ovfcnt, 1);
        ovflist[o] = e;
    }
}

// ---------------- gather: wave per node; read bf16 x, accumulate f32, write bf16 agg ----------------
__global__ __launch_bounds__(256) void gatherb_kernel(
    const int2* __restrict__ csr, const int* __restrict__ deg,
    unsigned short* __restrict__ ab, float* __restrict__ s, int nN, int cap) {
    int wid = (blockIdx.x * blockDim.x + threadIdx.x) >> 6;
    int lane = threadIdx.x & 63;
    if (wid >= nN) return;
    int dg = deg[wid];
    if (dg > cap) dg = cap;
    float a00 = 0.f, a01 = 0.f, a10 = 0.f, a11 = 0.f, a20 = 0.f, a21 = 0.f;
    float sw0 = 0.f, sw1 = 0.f, sw2 = 0.f;
    const int2* c = csr + (size_t)wid * cap;
    for (int i = 0; i < dg; ++i) {
        int2 e = c[i];
        int src = e.x & 0xFFFFF;
        int t = e.x >> 20;
        float w = __int_as_float(e.y);
        unsigned int xu = *(const unsigned int*)(ab + (size_t)src * 512 + lane * 2);
        float x0 = __uint_as_float(xu << 16);
        float x1 = __uint_as_float(xu & 0xFFFF0000u);
        float m0 = (t == 0) ? w : 0.f;
        float m1 = (t == 1) ? w : 0.f;
        float m2 = (t == 2) ? w : 0.f;
        a00 = fmaf(m0, x0, a00); a01 = fmaf(m0, x1, a01);
        a10 = fmaf(m1, x0, a10); a11 = fmaf(m1, x1, a11);
        a20 = fmaf(m2, x0, a20); a21 = fmaf(m2, x1, a21);
        sw0 += m0; sw1 += m1; sw2 += m2;
    }
    unsigned short* ap = ab + (size_t)wid * 512 + D;
    *(unsigned int*)(ap + 0 * D + lane * 2) = (unsigned int)f2bf(a00) | ((unsigned int)f2bf(a01) << 16);
    *(unsigned int*)(ap + 1 * D + lane * 2) = (unsigned int)f2bf(a10) | ((unsigned int)f2bf(a11) << 16);
    *(unsigned int*)(ap + 2 * D + lane * 2) = (unsigned int)f2bf(a20) | ((unsigned int)f2bf(a21) << 16);
    if (lane < 3) {
        float sv = (lane == 0) ? sw0 : ((lane == 1) ? sw1 : sw2);
        s[(size_t)wid * NT + lane] = sv;
    }
}

// ---------------- overflow fixup: ONE wave, serialized (cnt ~ 0 always) ----------------
__global__ __launch_bounds__(64) void ovf_fix_kernel(
    const int* __restrict__ ei, const int* __restrict__ et, const float* __restrict__ ew,
    const int* __restrict__ ovfcnt, const int* __restrict__ ovflist,
    unsigned short* __restrict__ ab, float* __restrict__ s, int nE) {
    int cnt = *ovfcnt;
    int lane = threadIdx.x;
    for (int i = 0; i < cnt; ++i) {
        int e = ovflist[i];
        int src = ei[e], dst = ei[nE + e], t = et[e];
        float w = ew[e];
        unsigned int xu = *(const unsigned int*)(ab + (size_t)src * 512 + lane * 2);
        float x0 = __uint_as_float(xu << 16);
        float x1 = __uint_as_float(xu & 0xFFFF0000u);
        unsigned short* p = ab + (size_t)dst * 512 + D + t * D + lane * 2;
        unsigned int au = *(unsigned int*)p;
        float v0 = __uint_as_float(au << 16) + w * x0;
        float v1 = __uint_as_float(au & 0xFFFF0000u) + w * x1;
        *(unsigned int*)p = (unsigned int)f2bf(v0) | ((unsigned int)f2bf(v1) << 16);
        if (lane == 0) s[(size_t)dst * NT + t] += w;
        __builtin_amdgcn_s_barrier();
    }
}

// ---------------- MFMA GEMM: out = gelu(ab @ B + biases) ----------------
__global__ __launch_bounds__(256) void mfma_gemm_kernel(
    const unsigned short* __restrict__ ab, const unsigned short* __restrict__ bfrag,
    const float* __restrict__ s, const float* __restrict__ biasb,
    float* __restrict__ out, int nN) {
    int tid = threadIdx.x;
    int wid = tid >> 6;
    int lane = tid & 63;
    int wr = wid >> 1, wc = wid & 1;
    int l15 = lane & 15;
    int lk8 = (lane >> 4) * 8;
    long row0 = (long)blockIdx.x * 128 + wr * 64;

    f32x4 acc[4][4];
#pragma unroll
    for (int i = 0; i < 4; ++i)
#pragma unroll
        for (int j = 0; j < 4; ++j) acc[i][j] = (f32x4){0.f, 0.f, 0.f, 0.f};

    int rA[4];
#pragma unroll
    for (int fr = 0; fr < 4; ++fr) {
        long r = row0 + fr * 16 + l15;
        rA[fr] = (r < nN) ? (int)r : (nN - 1);
    }

#pragma unroll 4
    for (int step = 0; step < 16; ++step) {
        bf16x8 aF[4], bF[4];
#pragma unroll
        for (int fr = 0; fr < 4; ++fr)
            aF[fr] = *(const bf16x8*)(ab + (size_t)rA[fr] * 512 + step * 32 + lk8);
#pragma unroll
        for (int fc = 0; fc < 4; ++fc)
            bF[fc] = *(const bf16x8*)(bfrag + (((size_t)step * 8 + wc * 4 + fc) * 64 + lane) * 8);
#pragma unroll
        for (int fr = 0; fr < 4; ++fr)
#pragma unroll
            for (int fc = 0; fc < 4; ++fc)
                acc[fr][fc] = __builtin_amdgcn_mfma_f32_16x16x32_bf16(aF[fr], bF[fc], acc[fr][fc], 0, 0, 0);
    }

    int colb = wc * 64 + l15;
    float bb0[4], bb1[4], bb2[4], bs4[4];
#pragma unroll
    for (int fc = 0; fc < 4; ++fc) {
        int c = colb + fc * 16;
        bb0[fc] = biasb[c]; bb1[fc] = biasb[D + c];
        bb2[fc] = biasb[2 * D + c]; bs4[fc] = biasb[3 * D + c];
    }
    const float kInvSqrt2 = 0.70710678118654752440f;
#pragma unroll
    for (int fr = 0; fr < 4; ++fr) {
#pragma unroll
        for (int reg = 0; reg < 4; ++reg) {
            long row = row0 + fr * 16 + (lane >> 4) * 4 + reg;
            if (row >= nN) continue;
            float s0 = s[row * NT + 0];
            float s1 = s[row * NT + 1];
            float s2 = s[row * NT + 2];
#pragma unroll
            for (int fc = 0; fc < 4; ++fc) {
                float v = acc[fr][fc][reg] + bs4[fc] + s0 * bb0[fc] + s1 * bb1[fc] + s2 * bb2[fc];
                v = 0.5f * v * (1.f + erff(v * kInvSqrt2));
                out[row * D + colb + fc * 16] = v;
            }
        }
    }
}

// ================= FALLBACK PATH (small ws): f32 atomic scatter + f32 GEMM =================
__global__ __launch_bounds__(256) void scatterA_kernel(
    const float* __restrict__ x, const int* __restrict__ ei,
    const int* __restrict__ et, const float* __restrict__ ew,
    float* __restrict__ agg, float* __restrict__ s, int nE) {
    int gtid = blockIdx.x * blockDim.x + threadIdx.x;
    int wave = gtid >> 6;
    int lane = threadIdx.x & 63;
    int nw = (gridDim.x * blockDim.x) >> 6;
    for (int e = wave; e < nE; e += nw) {
        int src = ei[e];
        int dst = ei[nE + e];
        int t = et[e];
        float w = ew[e];
        float2 xv = *(const float2*)(x + (size_t)src * D + lane * 2);
        float* p = agg + (size_t)dst * (NT * D) + t * D + lane * 2;
        unsafeAtomicAdd(p, w * xv.x);
        unsafeAtomicAdd(p + 1, w * xv.y);
        if (lane == 0) unsafeAtomicAdd(s + (size_t)dst * NT + t, w);
    }
}

#define BM 64
#define BK 32
__global__ __launch_bounds__(256) void gemm_gelu_kernel(
    const float* __restrict__ x, const float* __restrict__ agg,
    const float* __restrict__ s, const float* __restrict__ wcat,
    const float* __restrict__ biasb, float* __restrict__ out, int nNodes) {
    __shared__ float As[BK][BM + 1];
    __shared__ float Bs[BK][D];

    int tx = threadIdx.x;
    int row0 = blockIdx.x * BM;
    int cg = tx & 31;
    int rg = tx >> 5;
    int lr = tx >> 3;
    int lc = (tx & 7) * 4;

    float acc[8][4];
#pragma unroll
    for (int i = 0; i < 8; ++i)
#pragma unroll
        for (int j = 0; j < 4; ++j) acc[i][j] = 0.f;

    for (int k0 = 0; k0 < KTOT; k0 += BK) {
        const float* srcBase;
        int strideA, koff;
        if (k0 < D) { srcBase = x; strideA = D; koff = k0; }
        else        { srcBase = agg; strideA = NT * D; koff = k0 - D; }
#pragma unroll
        for (int h = 0; h < 2; ++h) {
            int r = lr + h * 32;
            int node = row0 + r;
            if (node >= nNodes) node = nNodes - 1;
            float4 v = *(const float4*)(srcBase + (size_t)node * strideA + koff + lc);
            As[lc + 0][r] = v.x; As[lc + 1][r] = v.y;
            As[lc + 2][r] = v.z; As[lc + 3][r] = v.w;
        }
        {
            int br = tx >> 5;
            int bc = (tx & 31) * 4;
#pragma unroll
            for (int h = 0; h < 4; ++h) {
                int r = br + h * 8;
                *(float4*)(&Bs[r][bc]) = *(const float4*)(wcat + (size_t)(k0 + r) * D + bc);
            }
        }
        __syncthreads();
#pragma unroll
        for (int kk = 0; kk < BK; ++kk) {
            float4 b = *(const float4*)(&Bs[kk][cg * 4]);
            float a[8];
            *(float4*)(a)     = *(const float4*)(&As[kk][rg * 8]);
            *(float4*)(a + 4) = *(const float4*)(&As[kk][rg * 8 + 4]);
#pragma unroll
            for (int i = 0; i < 8; ++i) {
                acc[i][0] = fmaf(a[i], b.x, acc[i][0]);
                acc[i][1] = fmaf(a[i], b.y, acc[i][1]);
                acc[i][2] = fmaf(a[i], b.z, acc[i][2]);
                acc[i][3] = fmaf(a[i], b.w, acc[i][3]);
            }
        }
        __syncthreads();
    }

    int jc = cg * 4;
    float4 bb0 = *(const float4*)(biasb + 0 * D + jc);
    float4 bb1 = *(const float4*)(biasb + 1 * D + jc);
    float4 bb2 = *(const float4*)(biasb + 2 * D + jc);
    float4 bsv = *(const float4*)(biasb + NT * D + jc);
#pragma unroll
    for (int i = 0; i < 8; ++i) {
        int node = row0 + rg * 8 + i;
        if (node >= nNodes) break;
        float s0 = s[(size_t)node * NT + 0];
        float s1 = s[(size_t)node * NT + 1];
        float s2 = s[(size_t)node * NT + 2];
        float4 r;
        r.x = acc[i][0] + bsv.x + s0 * bb0.x + s1 * bb1.x + s2 * bb2.x;
        r.y = acc[i][1] + bsv.y + s0 * bb0.y + s1 * bb1.y + s2 * bb2.y;
        r.z = acc[i][2] + bsv.z + s0 * bb0.z + s1 * bb1.z + s2 * bb2.z;
        r.w = acc[i][3] + bsv.w + s0 * bb0.w + s1 * bb1.w + s2 * bb2.w;
        const float kInvSqrt2 = 0.70710678118654752440f;
        r.x = 0.5f * r.x * (1.f + erff(r.x * kInvSqrt2));
        r.y = 0.5f * r.y * (1.f + erff(r.y * kInvSqrt2));
        r.z = 0.5f * r.z * (1.f + erff(r.z * kInvSqrt2));
        r.w = 0.5f * r.w * (1.f + erff(r.w * kInvSqrt2));
        *(float4*)(out + (size_t)node * D + jc) = r;
    }
}

// ================= PATH C: zero-workspace fallback =================
__global__ __launch_bounds__(256) void selfmv_kernel(
    const float* __restrict__ x, const float* __restrict__ Ws,
    const float* __restrict__ bs, const float* __restrict__ attn,
    float* __restrict__ out, int nN) {
    float a0 = attn[0], a1 = attn[1], a2 = attn[2], a3 = attn[3];
    float m = fmaxf(fmaxf(a0, a1), fmaxf(a2, a3));
    float e3 = expf(a3 - m);
    float inv = 1.f / (expf(a0 - m) + expf(a1 - m) + expf(a2 - m) + e3);
    float at3 = e3 * inv;
    int wave = (blockIdx.x * blockDim.x + threadIdx.x) >> 6;
    int lane = threadIdx.x & 63;
    int nw = (gridDim.x * blockDim.x) >> 6;
    for (int n = wave; n < nN; n += nw) {
        float2 xr = *(const float2*)(x + (size_t)n * D + lane * 2);
        float acc0 = 0.f, acc1 = 0.f;
#pragma unroll
        for (int k = 0; k < D; ++k) {
            float xv = __shfl((k & 1) ? xr.y : xr.x, k >> 1);
            float2 wv = *(const float2*)(Ws + (size_t)k * D + lane * 2);
            acc0 = fmaf(xv, wv.x, acc0);
            acc1 = fmaf(xv, wv.y, acc1);
        }
        float2 r;
        r.x = at3 * (acc0 + bs[lane * 2]);
        r.y = at3 * (acc1 + bs[lane * 2 + 1]);
        *(float2*)(out + (size_t)n * D + lane * 2) = r;
    }
}

__global__ __launch_bounds__(256) void edgemv_kernel(
    const float* __restrict__ x, const int* __restrict__ ei,
    const int* __restrict__ et, const float* __restrict__ ew,
    const float* __restrict__ We, const float* __restrict__ be,
    const float* __restrict__ attn, float* __restrict__ out, int nE) {
    float a0 = attn[0], a1 = attn[1], a2 = attn[2], a3 = attn[3];
    float m = fmaxf(fmaxf(a0, a1), fmaxf(a2, a3));
    float e0 = expf(a0 - m), e1 = expf(a1 - m), e2 = expf(a2 - m), e3 = expf(a3 - m);
    float inv = 1.f / (e0 + e1 + e2 + e3);
    float at[NT] = {e0 * inv, e1 * inv, e2 * inv};
    int wave = (blockIdx.x * blockDim.x + threadIdx.x) >> 6;
    int lane = threadIdx.x & 63;
    int nw = (gridDim.x * blockDim.x) >> 6;
    for (int e = wave; e < nE; e += nw) {
        int src = ei[e];
        int dst = ei[nE + e];
        int t = et[e];
        float sc = ew[e] * at[t];
        const float* W = We + (size_t)t * D * D;
        float2 xr = *(const float2*)(x + (size_t)src * D + lane * 2);
        float acc0 = 0.f, acc1 = 0.f;
#pragma unroll
        for (int k = 0; k < D; ++k) {
            float xv = __shfl((k & 1) ? xr.y : xr.x, k >> 1);
            float2 wv = *(const float2*)(W + (size_t)k * D + lane * 2);
            acc0 = fmaf(xv, wv.x, acc0);
            acc1 = fmaf(xv, wv.y, acc1);
        }
        float* p = out + (size_t)dst * D + lane * 2;
        unsafeAtomicAdd(p,     sc * (acc0 + be[(size_t)t * D + lane * 2]));
        unsafeAtomicAdd(p + 1, sc * (acc1 + be[(size_t)t * D + lane * 2 + 1]));
    }
}

__global__ void gelu_kernel(float* __restrict__ p, long long n4) {
    long long i = (long long)blockIdx.x * blockDim.x + threadIdx.x;
    long long stride = (long long)gridDim.x * blockDim.x;
    const float kInvSqrt2 = 0.70710678118654752440f;
    for (; i < n4; i += stride) {
        float4 r = ((float4*)p)[i];
        r.x = 0.5f * r.x * (1.f + erff(r.x * kInvSqrt2));
        r.y = 0.5f * r.y * (1.f + erff(r.y * kInvSqrt2));
        r.z = 0.5f * r.z * (1.f + erff(r.z * kInvSqrt2));
        r.w = 0.5f * r.w * (1.f + erff(r.w * kInvSqrt2));
        ((float4*)p)[i] = r;
    }
}

extern "C" void kernel_launch(void* const* d_in, const int* in_sizes, int n_in,
                              void* d_out, int out_size, void* d_ws, size_t ws_size,
                              hipStream_t stream) {
    const float* x = (const float*)d_in[0];
    const int* ei = (const int*)d_in[1];      // int64 in reference -> int32 here
    const int* et = (const int*)d_in[2];
    const float* ew = (const float*)d_in[3];
    const float* W_edge = (const float*)d_in[4];
    const float* b_edge = (const float*)d_in[5];
    const float* W_self = (const float*)d_in[6];
    const float* b_self = (const float*)d_in[7];
    const float* attention = (const float*)d_in[8];
    float* out = (float*)d_out;

    const int nN = in_sizes[0] / D;   // 100000
    const int nE = in_sizes[2];       // 600000

    // ---- gather+MFMA path sizing ----
    int cap = 0;
    const int capCand[3] = {32, 24, 16};
    for (int ci = 0; ci < 3; ++ci) {
        int c = capCand[ci];
        size_t need = (size_t)nN * 1024            // ab bf16
                    + (size_t)nN * 12              // s
                    + (size_t)KTOT * D * 4         // wcat (fallback consistency)
                    + (size_t)KTOT * 4             // biasb
                    + 131072                       // bfrag
                    + 4 * ((size_t)nN + 2 + (size_t)nE)
                    + 8ull * nN * c;               // csr
        if (ws_size >= need) { cap = c; break; }
    }

    if (cap > 0) {
        unsigned short* ab = (unsigned short*)d_ws;            // nN*512
        float* sW = (float*)(ab + (size_t)nN * 512);           // nN*3
        float* wcat = sW + (size_t)nN * NT;                    // 512*128
        float* biasb = wcat + (size_t)KTOT * D;                // 512
        unsigned short* bfrag = (unsigned short*)(biasb + KTOT); // 65536
        int* deg = (int*)(bfrag + 65536);                      // nN
        int* ovfc = deg + nN;                                  // 2
        int* ovfl = ovfc + 2;                                  // nE
        int2* csr = (int2*)(ovfl + nE);                        // nN*cap

        hipLaunchKernelGGL(zeroi_kernel, dim3(128), dim3(256), 0, stream, deg, nN + 2);
        hipLaunchKernelGGL(prep_kernel, dim3(64), dim3(256), 0, stream,
                           W_edge, b_edge, W_self, b_self, attention, wcat, biasb, bfrag);
        hipLaunchKernelGGL(xcvt_kernel, dim3(2048), dim3(256), 0, stream, x, ab, nN);
        hipLaunchKernelGGL(fill_kernel, dim3((nE + 255) / 256), dim3(256), 0, stream,
                           ei, et, ew, deg, csr, ovfc, ovfl, nE, cap);
        hipLaunchKernelGGL(gatherb_kernel, dim3((nN + 3) / 4), dim3(256), 0, stream,
                           csr, deg, ab, sW, nN, cap);
        hipLaunchKernelGGL(ovf_fix_kernel, dim3(1), dim3(64), 0, stream,
                           ei, et, ew, ovfc, ovfl, ab, sW, nE);
        hipLaunchKernelGGL(mfma_gemm_kernel, dim3((nN + 127) / 128), dim3(256), 0, stream,
                           ab, bfrag, sW, biasb, out, nN);
        return;
    }

    const size_t baseFloats = (size_t)nN * NT * D + (size_t)nN * NT + (size_t)KTOT * D + KTOT;
    if (ws_size >= baseFloats * 4) {
        // ---- atomic scatter + f32 GEMM fallback ----
        float* agg = (float*)d_ws;
        float* sW = agg + (size_t)nN * NT * D;
        float* wcat = sW + (size_t)nN * NT;
        float* biasb = wcat + (size_t)KTOT * D;
        long long zeroFloats = (long long)nN * (NT * D + NT);
        hipLaunchKernelGGL(zero_kernel, dim3(2048), dim3(256), 0, stream, agg, (zeroFloats + 3) / 4);
        hipLaunchKernelGGL(prep_kernel, dim3(64), dim3(256), 0, stream,
                           W_edge, b_edge, W_self, b_self, attention, wcat, biasb, (unsigned short*)nullptr);
        hipLaunchKernelGGL(scatterA_kernel, dim3(2048), dim3(256), 0, stream,
                           x, ei, et, ew, agg, sW, nE);
        hipLaunchKernelGGL(gemm_gelu_kernel, dim3((nN + BM - 1) / BM), dim3(256), 0, stream,
                           x, agg, sW, wcat, biasb, out, nN);
    } else {
        hipLaunchKernelGGL(selfmv_kernel, dim3(2048), dim3(256), 0, stream,
                           x, W_self, b_self, attention, out, nN);
        hipLaunchKernelGGL(edgemv_kernel, dim3(2048), dim3(256), 0, stream,
                           x, ei, et, ew, W_edge, b_edge, attention, out, nE);
        hipLaunchKernelGGL(gelu_kernel, dim3(2048), dim3(256), 0, stream,
                           out, (long long)nN * D / 4);
    }
}

// Round 5
// 158.698 us; speedup vs baseline: 4.8215x; 1.2109x over previous
//
#include <hip/hip_runtime.h>
#include <hip/hip_bf16.h>
#include <math.h>

#define D 128
#define NT 3
#define KTOT (D * (NT + 1))   // 512

typedef __attribute__((ext_vector_type(8))) __bf16 bf16x8;
typedef __attribute__((ext_vector_type(4))) float f32x4;

__device__ inline unsigned short f2bf(float f) {
    unsigned int u = __float_as_uint(f);
    unsigned int r = (u + 0x7FFFu + ((u >> 16) & 1u)) >> 16;
    return (unsigned short)r;
}

// ---------------- zero helpers ----------------
__global__ void zero_kernel(float* __restrict__ p, long long n4) {
    long long i = (long long)blockIdx.x * blockDim.x + threadIdx.x;
    long long stride = (long long)gridDim.x * blockDim.x;
    float4 z = make_float4(0.f, 0.f, 0.f, 0.f);
    for (; i < n4; i += stride) ((float4*)p)[i] = z;
}

__global__ void zeroi_kernel(int* __restrict__ p, int n) {
    int i = blockIdx.x * blockDim.x + threadIdx.x;
    int st = gridDim.x * blockDim.x;
    for (; i < n; i += st) p[i] = 0;
}

// ---------------- prep ----------------
__global__ void prep_kernel(const float* __restrict__ W_edge, const float* __restrict__ b_edge,
                            const float* __restrict__ W_self, const float* __restrict__ b_self,
                            const float* __restrict__ attention,
                            float* __restrict__ wcat, float* __restrict__ biasb,
                            unsigned short* __restrict__ bfrag) {
    float a0 = attention[0], a1 = attention[1], a2 = attention[2], a3 = attention[3];
    float m = fmaxf(fmaxf(a0, a1), fmaxf(a2, a3));
    float e0 = expf(a0 - m), e1 = expf(a1 - m), e2 = expf(a2 - m), e3 = expf(a3 - m);
    float inv = 1.f / (e0 + e1 + e2 + e3);
    float at[4] = {e0 * inv, e1 * inv, e2 * inv, e3 * inv};

    int idx0 = blockIdx.x * blockDim.x + threadIdx.x;
    int stride = gridDim.x * blockDim.x;
    for (int i = idx0; i < KTOT * D; i += stride) {
        int k = i >> 7, j = i & (D - 1);
        float v;
        if (k < D) {
            v = at[NT] * W_self[k * D + j];
        } else {
            int t = (k - D) >> 7;
            int kk = (k - D) & (D - 1);
            v = at[t] * W_edge[(t * D + kk) * D + j];
        }
        wcat[i] = v;
    }
    for (int i = idx0; i < KTOT; i += stride) {
        if (i < NT * D) {
            int t = i >> 7, j = i & (D - 1);
            biasb[i] = at[t] * b_edge[t * D + j];
        } else {
            biasb[i] = at[NT] * b_self[i - NT * D];
        }
    }
    // bfrag: [(step*8+cf)*64+lane]*8 ; B[k][col], col=cf*16+(l&15), k=step*32+(l>>4)*8+j
    for (int i = idx0; i < 16 * 8 * 64; i += stride) {
        int l = i & 63;
        int cf = (i >> 6) & 7;
        int step = i >> 9;
        int col = cf * 16 + (l & 15);
        int kb = step * 32 + ((l >> 4) * 8);
#pragma unroll
        for (int j = 0; j < 8; ++j) {
            int k = kb + j;
            float v;
            if (k < D) {
                v = at[NT] * W_self[k * D + col];
            } else {
                int t = (k - D) >> 7;
                int kk = (k - D) & (D - 1);
                v = at[t] * W_edge[(t * D + kk) * D + col];
            }
            bfrag[(size_t)i * 8 + j] = f2bf(v);
        }
    }
}

// ---------------- x -> bf16 into ab[:, 0:128] ----------------
__global__ __launch_bounds__(256) void xcvt_kernel(
    const float* __restrict__ x, unsigned short* __restrict__ ab, int nN) {
    int i = blockIdx.x * blockDim.x + threadIdx.x;
    int total = nN * (D / 4);
    int stride = gridDim.x * blockDim.x;
    for (; i < total; i += stride) {
        int n = i >> 5;
        int c4 = (i & 31) * 4;
        float4 v = *(const float4*)(x + (size_t)n * D + c4);
        ushort4 o;
        o.x = f2bf(v.x); o.y = f2bf(v.y); o.z = f2bf(v.z); o.w = f2bf(v.w);
        *(ushort4*)(ab + (size_t)n * 512 + c4) = o;
    }
}

// ---------------- fill: bucket edges by dst ----------------
__global__ __launch_bounds__(256) void fill_kernel(
    const int* __restrict__ ei, const int* __restrict__ et, const float* __restrict__ ew,
    int* __restrict__ deg, int2* __restrict__ csr, int* __restrict__ ovfcnt,
    int* __restrict__ ovflist, int nE, int cap) {
    int e = blockIdx.x * blockDim.x + threadIdx.x;
    if (e >= nE) return;
    int dst = ei[nE + e];
    int pos = atomicAdd(deg + dst, 1);
    if (pos < cap) {
        int src = ei[e];
        int t = et[e];
        csr[(size_t)dst * cap + pos] = make_int2(src | (t << 20), __float_as_int(ew[e]));
    } else {
        int o = atomicAdd(ovfcnt, 1);
        ovflist[o] = e;
    }
}

// ---------------- gather v2: 4 nodes/wave (16 lanes each), reg-prefetched metas, 2x unroll ----------------
__global__ __launch_bounds__(256) void gatherb_kernel(
    const int2* __restrict__ csr, const int* __restrict__ deg,
    unsigned short* __restrict__ ab, float* __restrict__ s, int nN, int cap) {
    int wid = (blockIdx.x * blockDim.x + threadIdx.x) >> 6;
    int lane = threadIdx.x & 63;
    int gl = lane & 15;          // lane within 16-lane group
    int base = lane & 48;        // group base lane
    int node = wid * 4 + (lane >> 4);
    int nclamp = (node < nN) ? node : (nN - 1);
    int dg = deg[nclamp];
    if (dg > cap) dg = cap;
    if (node >= nN) dg = 0;
    const int2* c = csr + (size_t)nclamp * cap;
    int2 mA = (gl < dg) ? c[gl] : make_int2(0, 0);
    int2 mB = (gl + 16 < dg) ? c[gl + 16] : make_int2(0, 0);

    float ac0[8], ac1[8], ac2[8];
#pragma unroll
    for (int j = 0; j < 8; ++j) { ac0[j] = 0.f; ac1[j] = 0.f; ac2[j] = 0.f; }
    float sw0 = 0.f, sw1 = 0.f, sw2 = 0.f;

    for (int i = 0; i < dg; i += 2) {
        // edge i (always active since i < dg)
        int slA = base + (i & 15);
        int exA = __shfl((i < 16) ? mA.x : mB.x, slA);
        int ewA = __shfl((i < 16) ? mA.y : mB.y, slA);
        int srcA = exA & 0xFFFFF;
        if (srcA >= nN) srcA = 0;
        float wA = __int_as_float(ewA);
        int tA = (exA >> 20) & 3;
        // edge i+1 (may be inactive)
        bool actB = (i + 1 < dg);
        int slB = base + ((i + 1) & 15);
        int exB = __shfl((i + 1 < 16) ? mA.x : mB.x, slB);
        int ewB = __shfl((i + 1 < 16) ? mA.y : mB.y, slB);
        int srcB = exB & 0xFFFFF;
        if (!actB || srcB >= nN) srcB = 0;
        float wB = actB ? __int_as_float(ewB) : 0.f;
        int tB = (exB >> 20) & 3;

        // both gathers issued before use
        uint4 xa = *(const uint4*)(ab + (size_t)srcA * 512 + gl * 8);
        uint4 xb = *(const uint4*)(ab + (size_t)srcB * 512 + gl * 8);

        float wA0 = (tA == 0) ? wA : 0.f;
        float wA1 = (tA == 1) ? wA : 0.f;
        float wA2 = (tA == 2) ? wA : 0.f;
        float wB0 = (tB == 0) ? wB : 0.f;
        float wB1 = (tB == 1) ? wB : 0.f;
        float wB2 = (tB == 2) ? wB : 0.f;
        sw0 += wA0 + wB0; sw1 += wA1 + wB1; sw2 += wA2 + wB2;

        float f0, f1;
#define ACCUM(u, j0, j1, w0_, w1_, w2_)                                   \
        f0 = __uint_as_float((u) << 16);                                  \
        f1 = __uint_as_float((u) & 0xFFFF0000u);                          \
        ac0[j0] = fmaf(w0_, f0, ac0[j0]); ac0[j1] = fmaf(w0_, f1, ac0[j1]); \
        ac1[j0] = fmaf(w1_, f0, ac1[j0]); ac1[j1] = fmaf(w1_, f1, ac1[j1]); \
        ac2[j0] = fmaf(w2_, f0, ac2[j0]); ac2[j1] = fmaf(w2_, f1, ac2[j1]);

        ACCUM(xa.x, 0, 1, wA0, wA1, wA2)
        ACCUM(xa.y, 2, 3, wA0, wA1, wA2)
        ACCUM(xa.z, 4, 5, wA0, wA1, wA2)
        ACCUM(xa.w, 6, 7, wA0, wA1, wA2)
        ACCUM(xb.x, 0, 1, wB0, wB1, wB2)
        ACCUM(xb.y, 2, 3, wB0, wB1, wB2)
        ACCUM(xb.z, 4, 5, wB0, wB1, wB2)
        ACCUM(xb.w, 6, 7, wB0, wB1, wB2)
#undef ACCUM
    }

    if (node < nN) {
        unsigned short* ap = ab + (size_t)node * 512 + D;
        uint4 o;
#define PACK(arr)                                                           \
        o.x = (unsigned int)f2bf(arr[0]) | ((unsigned int)f2bf(arr[1]) << 16); \
        o.y = (unsigned int)f2bf(arr[2]) | ((unsigned int)f2bf(arr[3]) << 16); \
        o.z = (unsigned int)f2bf(arr[4]) | ((unsigned int)f2bf(arr[5]) << 16); \
        o.w = (unsigned int)f2bf(arr[6]) | ((unsigned int)f2bf(arr[7]) << 16);
        PACK(ac0) *(uint4*)(ap + 0 * D + gl * 8) = o;
        PACK(ac1) *(uint4*)(ap + 1 * D + gl * 8) = o;
        PACK(ac2) *(uint4*)(ap + 2 * D + gl * 8) = o;
#undef PACK
        if (gl < 3) {
            float sv = (gl == 0) ? sw0 : ((gl == 1) ? sw1 : sw2);
            s[(size_t)node * NT + gl] = sv;
        }
    }
}

// ---------------- overflow fixup: ONE wave, serialized (cnt ~ 0 always) ----------------
__global__ __launch_bounds__(64) void ovf_fix_kernel(
    const int* __restrict__ ei, const int* __restrict__ et, const float* __restrict__ ew,
    const int* __restrict__ ovfcnt, const int* __restrict__ ovflist,
    unsigned short* __restrict__ ab, float* __restrict__ s, int nE) {
    int cnt = *ovfcnt;
    int lane = threadIdx.x;
    for (int i = 0; i < cnt; ++i) {
        int e = ovflist[i];
        int src = ei[e], dst = ei[nE + e], t = et[e];
        float w = ew[e];
        unsigned int xu = *(const unsigned int*)(ab + (size_t)src * 512 + lane * 2);
        float x0 = __uint_as_float(xu << 16);
        float x1 = __uint_as_float(xu & 0xFFFF0000u);
        unsigned short* p = ab + (size_t)dst * 512 + D + t * D + lane * 2;
        unsigned int au = *(unsigned int*)p;
        float v0 = __uint_as_float(au << 16) + w * x0;
        float v1 = __uint_as_float(au & 0xFFFF0000u) + w * x1;
        *(unsigned int*)p = (unsigned int)f2bf(v0) | ((unsigned int)f2bf(v1) << 16);
        if (lane == 0) s[(size_t)dst * NT + t] += w;
        __builtin_amdgcn_s_barrier();
    }
}

// ---------------- MFMA GEMM: out = gelu(ab @ B + biases) ----------------
__global__ __launch_bounds__(256) void mfma_gemm_kernel(
    const unsigned short* __restrict__ ab, const unsigned short* __restrict__ bfrag,
    const float* __restrict__ s, const float* __restrict__ biasb,
    float* __restrict__ out, int nN) {
    int tid = threadIdx.x;
    int wid = tid >> 6;
    int lane = tid & 63;
    int wr = wid >> 1, wc = wid & 1;
    int l15 = lane & 15;
    int lk8 = (lane >> 4) * 8;
    long row0 = (long)blockIdx.x * 128 + wr * 64;

    f32x4 acc[4][4];
#pragma unroll
    for (int i = 0; i < 4; ++i)
#pragma unroll
        for (int j = 0; j < 4; ++j) acc[i][j] = (f32x4){0.f, 0.f, 0.f, 0.f};

    int rA[4];
#pragma unroll
    for (int fr = 0; fr < 4; ++fr) {
        long r = row0 + fr * 16 + l15;
        rA[fr] = (r < nN) ? (int)r : (nN - 1);
    }

#pragma unroll 4
    for (int step = 0; step < 16; ++step) {
        bf16x8 aF[4], bF[4];
#pragma unroll
        for (int fr = 0; fr < 4; ++fr)
            aF[fr] = *(const bf16x8*)(ab + (size_t)rA[fr] * 512 + step * 32 + lk8);
#pragma unroll
        for (int fc = 0; fc < 4; ++fc)
            bF[fc] = *(const bf16x8*)(bfrag + (((size_t)step * 8 + wc * 4 + fc) * 64 + lane) * 8);
#pragma unroll
        for (int fr = 0; fr < 4; ++fr)
#pragma unroll
            for (int fc = 0; fc < 4; ++fc)
                acc[fr][fc] = __builtin_amdgcn_mfma_f32_16x16x32_bf16(aF[fr], bF[fc], acc[fr][fc], 0, 0, 0);
    }

    int colb = wc * 64 + l15;
    float bb0[4], bb1[4], bb2[4], bs4[4];
#pragma unroll
    for (int fc = 0; fc < 4; ++fc) {
        int c = colb + fc * 16;
        bb0[fc] = biasb[c]; bb1[fc] = biasb[D + c];
        bb2[fc] = biasb[2 * D + c]; bs4[fc] = biasb[3 * D + c];
    }
    const float kInvSqrt2 = 0.70710678118654752440f;
#pragma unroll
    for (int fr = 0; fr < 4; ++fr) {
#pragma unroll
        for (int reg = 0; reg < 4; ++reg) {
            long row = row0 + fr * 16 + (lane >> 4) * 4 + reg;
            if (row >= nN) continue;
            float s0 = s[row * NT + 0];
            float s1 = s[row * NT + 1];
            float s2 = s[row * NT + 2];
#pragma unroll
            for (int fc = 0; fc < 4; ++fc) {
                float v = acc[fr][fc][reg] + bs4[fc] + s0 * bb0[fc] + s1 * bb1[fc] + s2 * bb2[fc];
                v = 0.5f * v * (1.f + erff(v * kInvSqrt2));
                out[row * D + colb + fc * 16] = v;
            }
        }
    }
}

// ================= FALLBACK PATH (small ws): f32 atomic scatter + f32 GEMM =================
__global__ __launch_bounds__(256) void scatterA_kernel(
    const float* __restrict__ x, const int* __restrict__ ei,
    const int* __restrict__ et, const float* __restrict__ ew,
    float* __restrict__ agg, float* __restrict__ s, int nE) {
    int gtid = blockIdx.x * blockDim.x + threadIdx.x;
    int wave = gtid >> 6;
    int lane = threadIdx.x & 63;
    int nw = (gridDim.x * blockDim.x) >> 6;
    for (int e = wave; e < nE; e += nw) {
        int src = ei[e];
        int dst = ei[nE + e];
        int t = et[e];
        float w = ew[e];
        float2 xv = *(const float2*)(x + (size_t)src * D + lane * 2);
        float* p = agg + (size_t)dst * (NT * D) + t * D + lane * 2;
        unsafeAtomicAdd(p, w * xv.x);
        unsafeAtomicAdd(p + 1, w * xv.y);
        if (lane == 0) unsafeAtomicAdd(s + (size_t)dst * NT + t, w);
    }
}

#define BM 64
#define BK 32
__global__ __launch_bounds__(256) void gemm_gelu_kernel(
    const float* __restrict__ x, const float* __restrict__ agg,
    const float* __restrict__ s, const float* __restrict__ wcat,
    const float* __restrict__ biasb, float* __restrict__ out, int nNodes) {
    __shared__ float As[BK][BM + 1];
    __shared__ float Bs[BK][D];

    int tx = threadIdx.x;
    int row0 = blockIdx.x * BM;
    int cg = tx & 31;
    int rg = tx >> 5;
    int lr = tx >> 3;
    int lc = (tx & 7) * 4;

    float acc[8][4];
#pragma unroll
    for (int i = 0; i < 8; ++i)
#pragma unroll
        for (int j = 0; j < 4; ++j) acc[i][j] = 0.f;

    for (int k0 = 0; k0 < KTOT; k0 += BK) {
        const float* srcBase;
        int strideA, koff;
        if (k0 < D) { srcBase = x; strideA = D; koff = k0; }
        else        { srcBase = agg; strideA = NT * D; koff = k0 - D; }
#pragma unroll
        for (int h = 0; h < 2; ++h) {
            int r = lr + h * 32;
            int node = row0 + r;
            if (node >= nNodes) node = nNodes - 1;
            float4 v = *(const float4*)(srcBase + (size_t)node * strideA + koff + lc);
            As[lc + 0][r] = v.x; As[lc + 1][r] = v.y;
            As[lc + 2][r] = v.z; As[lc + 3][r] = v.w;
        }
        {
            int br = tx >> 5;
            int bc = (tx & 31) * 4;
#pragma unroll
            for (int h = 0; h < 4; ++h) {
                int r = br + h * 8;
                *(float4*)(&Bs[r][bc]) = *(const float4*)(wcat + (size_t)(k0 + r) * D + bc);
            }
        }
        __syncthreads();
#pragma unroll
        for (int kk = 0; kk < BK; ++kk) {
            float4 b = *(const float4*)(&Bs[kk][cg * 4]);
            float a[8];
            *(float4*)(a)     = *(const float4*)(&As[kk][rg * 8]);
            *(float4*)(a + 4) = *(const float4*)(&As[kk][rg * 8 + 4]);
#pragma unroll
            for (int i = 0; i < 8; ++i) {
                acc[i][0] = fmaf(a[i], b.x, acc[i][0]);
                acc[i][1] = fmaf(a[i], b.y, acc[i][1]);
                acc[i][2] = fmaf(a[i], b.z, acc[i][2]);
                acc[i][3] = fmaf(a[i], b.w, acc[i][3]);
            }
        }
        __syncthreads();
    }

    int jc = cg * 4;
    float4 bb0 = *(const float4*)(biasb + 0 * D + jc);
    float4 bb1 = *(const float4*)(biasb + 1 * D + jc);
    float4 bb2 = *(const float4*)(biasb + 2 * D + jc);
    float4 bsv = *(const float4*)(biasb + NT * D + jc);
#pragma unroll
    for (int i = 0; i < 8; ++i) {
        int node = row0 + rg * 8 + i;
        if (node >= nNodes) break;
        float s0 = s[(size_t)node * NT + 0];
        float s1 = s[(size_t)node * NT + 1];
        float s2 = s[(size_t)node * NT + 2];
        float4 r;
        r.x = acc[i][0] + bsv.x + s0 * bb0.x + s1 * bb1.x + s2 * bb2.x;
        r.y = acc[i][1] + bsv.y + s0 * bb0.y + s1 * bb1.y + s2 * bb2.y;
        r.z = acc[i][2] + bsv.z + s0 * bb0.z + s1 * bb1.z + s2 * bb2.z;
        r.w = acc[i][3] + bsv.w + s0 * bb0.w + s1 * bb1.w + s2 * bb2.w;
        const float kInvSqrt2 = 0.70710678118654752440f;
        r.x = 0.5f * r.x * (1.f + erff(r.x * kInvSqrt2));
        r.y = 0.5f * r.y * (1.f + erff(r.y * kInvSqrt2));
        r.z = 0.5f * r.z * (1.f + erff(r.z * kInvSqrt2));
        r.w = 0.5f * r.w * (1.f + erff(r.w * kInvSqrt2));
        *(float4*)(out + (size_t)node * D + jc) = r;
    }
}

// ================= PATH C: zero-workspace fallback =================
__global__ __launch_bounds__(256) void selfmv_kernel(
    const float* __restrict__ x, const float* __restrict__ Ws,
    const float* __restrict__ bs, const float* __restrict__ attn,
    float* __restrict__ out, int nN) {
    float a0 = attn[0], a1 = attn[1], a2 = attn[2], a3 = attn[3];
    float m = fmaxf(fmaxf(a0, a1), fmaxf(a2, a3));
    float e3 = expf(a3 - m);
    float inv = 1.f / (expf(a0 - m) + expf(a1 - m) + expf(a2 - m) + e3);
    float at3 = e3 * inv;
    int wave = (blockIdx.x * blockDim.x + threadIdx.x) >> 6;
    int lane = threadIdx.x & 63;
    int nw = (gridDim.x * blockDim.x) >> 6;
    for (int n = wave; n < nN; n += nw) {
        float2 xr = *(const float2*)(x + (size_t)n * D + lane * 2);
        float acc0 = 0.f, acc1 = 0.f;
#pragma unroll
        for (int k = 0; k < D; ++k) {
            float xv = __shfl((k & 1) ? xr.y : xr.x, k >> 1);
            float2 wv = *(const float2*)(Ws + (size_t)k * D + lane * 2);
            acc0 = fmaf(xv, wv.x, acc0);
            acc1 = fmaf(xv, wv.y, acc1);
        }
        float2 r;
        r.x = at3 * (acc0 + bs[lane * 2]);
        r.y = at3 * (acc1 + bs[lane * 2 + 1]);
        *(float2*)(out + (size_t)n * D + lane * 2) = r;
    }
}

__global__ __launch_bounds__(256) void edgemv_kernel(
    const float* __restrict__ x, const int* __restrict__ ei,
    const int* __restrict__ et, const float* __restrict__ ew,
    const float* __restrict__ We, const float* __restrict__ be,
    const float* __restrict__ attn, float* __restrict__ out, int nE) {
    float a0 = attn[0], a1 = attn[1], a2 = attn[2], a3 = attn[3];
    float m = fmaxf(fmaxf(a0, a1), fmaxf(a2, a3));
    float e0 = expf(a0 - m), e1 = expf(a1 - m), e2 = expf(a2 - m), e3 = expf(a3 - m);
    float inv = 1.f / (e0 + e1 + e2 + e3);
    float at[NT] = {e0 * inv, e1 * inv, e2 * inv};
    int wave = (blockIdx.x * blockDim.x + threadIdx.x) >> 6;
    int lane = threadIdx.x & 63;
    int nw = (gridDim.x * blockDim.x) >> 6;
    for (int e = wave; e < nE; e += nw) {
        int src = ei[e];
        int dst = ei[nE + e];
        int t = et[e];
        float sc = ew[e] * at[t];
        const float* W = We + (size_t)t * D * D;
        float2 xr = *(const float2*)(x + (size_t)src * D + lane * 2);
        float acc0 = 0.f, acc1 = 0.f;
#pragma unroll
        for (int k = 0; k < D; ++k) {
            float xv = __shfl((k & 1) ? xr.y : xr.x, k >> 1);
            float2 wv = *(const float2*)(W + (size_t)k * D + lane * 2);
            acc0 = fmaf(xv, wv.x, acc0);
            acc1 = fmaf(xv, wv.y, acc1);
        }
        float* p = out + (size_t)dst * D + lane * 2;
        unsafeAtomicAdd(p,     sc * (acc0 + be[(size_t)t * D + lane * 2]));
        unsafeAtomicAdd(p + 1, sc * (acc1 + be[(size_t)t * D + lane * 2 + 1]));
    }
}

__global__ void gelu_kernel(float* __restrict__ p, long long n4) {
    long long i = (long long)blockIdx.x * blockDim.x + threadIdx.x;
    long long stride = (long long)gridDim.x * blockDim.x;
    const float kInvSqrt2 = 0.70710678118654752440f;
    for (; i < n4; i += stride) {
        float4 r = ((float4*)p)[i];
        r.x = 0.5f * r.x * (1.f + erff(r.x * kInvSqrt2));
        r.y = 0.5f * r.y * (1.f + erff(r.y * kInvSqrt2));
        r.z = 0.5f * r.z * (1.f + erff(r.z * kInvSqrt2));
        r.w = 0.5f * r.w * (1.f + erff(r.w * kInvSqrt2));
        ((float4*)p)[i] = r;
    }
}

extern "C" void kernel_launch(void* const* d_in, const int* in_sizes, int n_in,
                              void* d_out, int out_size, void* d_ws, size_t ws_size,
                              hipStream_t stream) {
    const float* x = (const float*)d_in[0];
    const int* ei = (const int*)d_in[1];      // int64 in reference -> int32 here
    const int* et = (const int*)d_in[2];
    const float* ew = (const float*)d_in[3];
    const float* W_edge = (const float*)d_in[4];
    const float* b_edge = (const float*)d_in[5];
    const float* W_self = (const float*)d_in[6];
    const float* b_self = (const float*)d_in[7];
    const float* attention = (const float*)d_in[8];
    float* out = (float*)d_out;

    const int nN = in_sizes[0] / D;   // 100000
    const int nE = in_sizes[2];       // 600000

    // ---- gather+MFMA path sizing ----
    int cap = 0;
    const int capCand[3] = {32, 24, 16};
    for (int ci = 0; ci < 3; ++ci) {
        int c = capCand[ci];
        size_t need = (size_t)nN * 1024            // ab bf16
                    + (size_t)nN * 12              // s
                    + (size_t)KTOT * D * 4         // wcat
                    + (size_t)KTOT * 4             // biasb
                    + 131072                       // bfrag
                    + 4 * ((size_t)nN + 2 + (size_t)nE)
                    + 8ull * nN * c;               // csr
        if (ws_size >= need) { cap = c; break; }
    }

    if (cap > 0) {
        unsigned short* ab = (unsigned short*)d_ws;            // nN*512
        float* sW = (float*)(ab + (size_t)nN * 512);           // nN*3
        float* wcat = sW + (size_t)nN * NT;                    // 512*128
        float* biasb = wcat + (size_t)KTOT * D;                // 512
        unsigned short* bfrag = (unsigned short*)(biasb + KTOT); // 65536
        int* deg = (int*)(bfrag + 65536);                      // nN
        int* ovfc = deg + nN;                                  // 2
        int* ovfl = ovfc + 2;                                  // nE
        int2* csr = (int2*)(ovfl + nE);                        // nN*cap

        hipLaunchKernelGGL(zeroi_kernel, dim3(128), dim3(256), 0, stream, deg, nN + 2);
        hipLaunchKernelGGL(prep_kernel, dim3(64), dim3(256), 0, stream,
                           W_edge, b_edge, W_self, b_self, attention, wcat, biasb, bfrag);
        hipLaunchKernelGGL(xcvt_kernel, dim3(2048), dim3(256), 0, stream, x, ab, nN);
        hipLaunchKernelGGL(fill_kernel, dim3((nE + 255) / 256), dim3(256), 0, stream,
                           ei, et, ew, deg, csr, ovfc, ovfl, nE, cap);
        hipLaunchKernelGGL(gatherb_kernel, dim3((nN + 15) / 16), dim3(256), 0, stream,
                           csr, deg, ab, sW, nN, cap);
        hipLaunchKernelGGL(ovf_fix_kernel, dim3(1), dim3(64), 0, stream,
                           ei, et, ew, ovfc, ovfl, ab, sW, nE);
        hipLaunchKernelGGL(mfma_gemm_kernel, dim3((nN + 127) / 128), dim3(256), 0, stream,
                           ab, bfrag, sW, biasb, out, nN);
        return;
    }

    const size_t baseFloats = (size_t)nN * NT * D + (size_t)nN * NT + (size_t)KTOT * D + KTOT;
    if (ws_size >= baseFloats * 4) {
        float* agg = (float*)d_ws;
        float* sW = agg + (size_t)nN * NT * D;
        float* wcat = sW + (size_t)nN * NT;
        float* biasb = wcat + (size_t)KTOT * D;
        long long zeroFloats = (long long)nN * (NT * D + NT);
        hipLaunchKernelGGL(zero_kernel, dim3(2048), dim3(256), 0, stream, agg, (zeroFloats + 3) / 4);
        hipLaunchKernelGGL(prep_kernel, dim3(64), dim3(256), 0, stream,
                           W_edge, b_edge, W_self, b_self, attention, wcat, biasb, (unsigned short*)wcat /*unused dummy, never the MFMA path*/);
        hipLaunchKernelGGL(scatterA_kernel, dim3(2048), dim3(256), 0, stream,
                           x, ei, et, ew, agg, sW, nE);
        hipLaunchKernelGGL(gemm_gelu_kernel, dim3((nN + BM - 1) / BM), dim3(256), 0, stream,
                           x, agg, sW, wcat, biasb, out, nN);
    } else {
        hipLaunchKernelGGL(selfmv_kernel, dim3(2048), dim3(256), 0, stream,
                           x, W_self, b_self, attention, out, nN);
        hipLaunchKernelGGL(edgemv_kernel, dim3(2048), dim3(256), 0, stream,
                           x, ei, et, ew, W_edge, b_edge, attention, out, nE);
        hipLaunchKernelGGL(gelu_kernel, dim3(2048), dim3(256), 0, stream,
                           out, (long long)nN * D / 4);
    }
}

// Round 6
// 130.642 us; speedup vs baseline: 5.8570x; 1.2148x over previous
//
#include <hip/hip_runtime.h>
#include <hip/hip_bf16.h>
#include <math.h>

#define D 128
#define NT 3
#define KTOT (D * (NT + 1))   // 512

typedef __attribute__((ext_vector_type(8))) __bf16 bf16x8;
typedef __attribute__((ext_vector_type(4))) float f32x4;

__device__ inline unsigned short f2bf(float f) {
    unsigned int u = __float_as_uint(f);
    unsigned int r = (u + 0x7FFFu + ((u >> 16) & 1u)) >> 16;
    return (unsigned short)r;
}

// ---------------- zero helpers ----------------
__global__ void zero_kernel(float* __restrict__ p, long long n4) {
    long long i = (long long)blockIdx.x * blockDim.x + threadIdx.x;
    long long stride = (long long)gridDim.x * blockDim.x;
    float4 z = make_float4(0.f, 0.f, 0.f, 0.f);
    for (; i < n4; i += stride) ((float4*)p)[i] = z;
}

__global__ void zeroi_kernel(int* __restrict__ p, int n) {
    int i = blockIdx.x * blockDim.x + threadIdx.x;
    int st = gridDim.x * blockDim.x;
    for (; i < n; i += st) p[i] = 0;
}

// ---------------- prep ----------------
__global__ void prep_kernel(const float* __restrict__ W_edge, const float* __restrict__ b_edge,
                            const float* __restrict__ W_self, const float* __restrict__ b_self,
                            const float* __restrict__ attention,
                            float* __restrict__ wcat, float* __restrict__ biasb,
                            unsigned short* __restrict__ bfrag) {
    float a0 = attention[0], a1 = attention[1], a2 = attention[2], a3 = attention[3];
    float m = fmaxf(fmaxf(a0, a1), fmaxf(a2, a3));
    float e0 = expf(a0 - m), e1 = expf(a1 - m), e2 = expf(a2 - m), e3 = expf(a3 - m);
    float inv = 1.f / (e0 + e1 + e2 + e3);
    float at[4] = {e0 * inv, e1 * inv, e2 * inv, e3 * inv};

    int idx0 = blockIdx.x * blockDim.x + threadIdx.x;
    int stride = gridDim.x * blockDim.x;
    for (int i = idx0; i < KTOT * D; i += stride) {
        int k = i >> 7, j = i & (D - 1);
        float v;
        if (k < D) {
            v = at[NT] * W_self[k * D + j];
        } else {
            int t = (k - D) >> 7;
            int kk = (k - D) & (D - 1);
            v = at[t] * W_edge[(t * D + kk) * D + j];
        }
        wcat[i] = v;
    }
    for (int i = idx0; i < KTOT; i += stride) {
        if (i < NT * D) {
            int t = i >> 7, j = i & (D - 1);
            biasb[i] = at[t] * b_edge[t * D + j];
        } else {
            biasb[i] = at[NT] * b_self[i - NT * D];
        }
    }
    // bfrag: [(step*8+cf)*64+lane]*8 ; B[k][col], col=cf*16+(l&15), k=step*32+(l>>4)*8+j
    for (int i = idx0; i < 16 * 8 * 64; i += stride) {
        int l = i & 63;
        int cf = (i >> 6) & 7;
        int step = i >> 9;
        int col = cf * 16 + (l & 15);
        int kb = step * 32 + ((l >> 4) * 8);
#pragma unroll
        for (int j = 0; j < 8; ++j) {
            int k = kb + j;
            float v;
            if (k < D) {
                v = at[NT] * W_self[k * D + col];
            } else {
                int t = (k - D) >> 7;
                int kk = (k - D) & (D - 1);
                v = at[t] * W_edge[(t * D + kk) * D + col];
            }
            bfrag[(size_t)i * 8 + j] = f2bf(v);
        }
    }
}

// ---------------- x -> bf16 into ab[:, 0:128] ----------------
__global__ __launch_bounds__(256) void xcvt_kernel(
    const float* __restrict__ x, unsigned short* __restrict__ ab, int nN) {
    int i = blockIdx.x * blockDim.x + threadIdx.x;
    int total = nN * (D / 4);
    int stride = gridDim.x * blockDim.x;
    for (; i < total; i += stride) {
        int n = i >> 5;
        int c4 = (i & 31) * 4;
        float4 v = *(const float4*)(x + (size_t)n * D + c4);
        ushort4 o;
        o.x = f2bf(v.x); o.y = f2bf(v.y); o.z = f2bf(v.z); o.w = f2bf(v.w);
        *(ushort4*)(ab + (size_t)n * 512 + c4) = o;
    }
}

// ---------------- fill: bucket edges by dst ----------------
__global__ __launch_bounds__(256) void fill_kernel(
    const int* __restrict__ ei, const int* __restrict__ et, const float* __restrict__ ew,
    int* __restrict__ deg, int2* __restrict__ csr, int* __restrict__ ovfcnt,
    int* __restrict__ ovflist, int nE, int cap) {
    int e = blockIdx.x * blockDim.x + threadIdx.x;
    if (e >= nE) return;
    int dst = ei[nE + e];
    int pos = atomicAdd(deg + dst, 1);
    if (pos < cap) {
        int src = ei[e];
        int t = et[e];
        csr[(size_t)dst * cap + pos] = make_int2(src | (t << 20), __float_as_int(ew[e]));
    } else {
        int o = atomicAdd(ovfcnt, 1);
        ovflist[o] = e;
    }
}

// ---------------- gather v2: 4 nodes/wave (16 lanes each), reg-prefetched metas, 2x unroll ----------------
__global__ __launch_bounds__(256) void gatherb_kernel(
    const int2* __restrict__ csr, const int* __restrict__ deg,
    unsigned short* __restrict__ ab, float* __restrict__ s, int nN, int cap) {
    int wid = (blockIdx.x * blockDim.x + threadIdx.x) >> 6;
    int lane = threadIdx.x & 63;
    int gl = lane & 15;          // lane within 16-lane group
    int base = lane & 48;        // group base lane
    int node = wid * 4 + (lane >> 4);
    int nclamp = (node < nN) ? node : (nN - 1);
    int dg = deg[nclamp];
    if (dg > cap) dg = cap;
    if (node >= nN) dg = 0;
    const int2* c = csr + (size_t)nclamp * cap;
    int2 mA = (gl < dg) ? c[gl] : make_int2(0, 0);
    int2 mB = (gl + 16 < dg) ? c[gl + 16] : make_int2(0, 0);

    float ac0[8], ac1[8], ac2[8];
#pragma unroll
    for (int j = 0; j < 8; ++j) { ac0[j] = 0.f; ac1[j] = 0.f; ac2[j] = 0.f; }
    float sw0 = 0.f, sw1 = 0.f, sw2 = 0.f;

    for (int i = 0; i < dg; i += 2) {
        int slA = base + (i & 15);
        int exA = __shfl((i < 16) ? mA.x : mB.x, slA);
        int ewA = __shfl((i < 16) ? mA.y : mB.y, slA);
        int srcA = exA & 0xFFFFF;
        if (srcA >= nN) srcA = 0;
        float wA = __int_as_float(ewA);
        int tA = (exA >> 20) & 3;
        bool actB = (i + 1 < dg);
        int slB = base + ((i + 1) & 15);
        int exB = __shfl((i + 1 < 16) ? mA.x : mB.x, slB);
        int ewB = __shfl((i + 1 < 16) ? mA.y : mB.y, slB);
        int srcB = exB & 0xFFFFF;
        if (!actB || srcB >= nN) srcB = 0;
        float wB = actB ? __int_as_float(ewB) : 0.f;
        int tB = (exB >> 20) & 3;

        uint4 xa = *(const uint4*)(ab + (size_t)srcA * 512 + gl * 8);
        uint4 xb = *(const uint4*)(ab + (size_t)srcB * 512 + gl * 8);

        float wA0 = (tA == 0) ? wA : 0.f;
        float wA1 = (tA == 1) ? wA : 0.f;
        float wA2 = (tA == 2) ? wA : 0.f;
        float wB0 = (tB == 0) ? wB : 0.f;
        float wB1 = (tB == 1) ? wB : 0.f;
        float wB2 = (tB == 2) ? wB : 0.f;
        sw0 += wA0 + wB0; sw1 += wA1 + wB1; sw2 += wA2 + wB2;

        float f0, f1;
#define ACCUM(u, j0, j1, w0_, w1_, w2_)                                   \
        f0 = __uint_as_float((u) << 16);                                  \
        f1 = __uint_as_float((u) & 0xFFFF0000u);                          \
        ac0[j0] = fmaf(w0_, f0, ac0[j0]); ac0[j1] = fmaf(w0_, f1, ac0[j1]); \
        ac1[j0] = fmaf(w1_, f0, ac1[j0]); ac1[j1] = fmaf(w1_, f1, ac1[j1]); \
        ac2[j0] = fmaf(w2_, f0, ac2[j0]); ac2[j1] = fmaf(w2_, f1, ac2[j1]);

        ACCUM(xa.x, 0, 1, wA0, wA1, wA2)
        ACCUM(xa.y, 2, 3, wA0, wA1, wA2)
        ACCUM(xa.z, 4, 5, wA0, wA1, wA2)
        ACCUM(xa.w, 6, 7, wA0, wA1, wA2)
        ACCUM(xb.x, 0, 1, wB0, wB1, wB2)
        ACCUM(xb.y, 2, 3, wB0, wB1, wB2)
        ACCUM(xb.z, 4, 5, wB0, wB1, wB2)
        ACCUM(xb.w, 6, 7, wB0, wB1, wB2)
#undef ACCUM
    }

    if (node < nN) {
        unsigned short* ap = ab + (size_t)node * 512 + D;
        uint4 o;
#define PACK(arr)                                                           \
        o.x = (unsigned int)f2bf(arr[0]) | ((unsigned int)f2bf(arr[1]) << 16); \
        o.y = (unsigned int)f2bf(arr[2]) | ((unsigned int)f2bf(arr[3]) << 16); \
        o.z = (unsigned int)f2bf(arr[4]) | ((unsigned int)f2bf(arr[5]) << 16); \
        o.w = (unsigned int)f2bf(arr[6]) | ((unsigned int)f2bf(arr[7]) << 16);
        PACK(ac0) *(uint4*)(ap + 0 * D + gl * 8) = o;
        PACK(ac1) *(uint4*)(ap + 1 * D + gl * 8) = o;
        PACK(ac2) *(uint4*)(ap + 2 * D + gl * 8) = o;
#undef PACK
        if (gl < 3) {
            float sv = (gl == 0) ? sw0 : ((gl == 1) ? sw1 : sw2);
            s[(size_t)node * NT + gl] = sv;
        }
    }
}

// ---------------- overflow fixup ----------------
__global__ __launch_bounds__(64) void ovf_fix_kernel(
    const int* __restrict__ ei, const int* __restrict__ et, const float* __restrict__ ew,
    const int* __restrict__ ovfcnt, const int* __restrict__ ovflist,
    unsigned short* __restrict__ ab, float* __restrict__ s, int nE) {
    int cnt = *ovfcnt;
    int lane = threadIdx.x;
    for (int i = 0; i < cnt; ++i) {
        int e = ovflist[i];
        int src = ei[e], dst = ei[nE + e], t = et[e];
        float w = ew[e];
        unsigned int xu = *(const unsigned int*)(ab + (size_t)src * 512 + lane * 2);
        float x0 = __uint_as_float(xu << 16);
        float x1 = __uint_as_float(xu & 0xFFFF0000u);
        unsigned short* p = ab + (size_t)dst * 512 + D + t * D + lane * 2;
        unsigned int au = *(unsigned int*)p;
        float v0 = __uint_as_float(au << 16) + w * x0;
        float v1 = __uint_as_float(au & 0xFFFF0000u) + w * x1;
        *(unsigned int*)p = (unsigned int)f2bf(v0) | ((unsigned int)f2bf(v1) << 16);
        if (lane == 0) s[(size_t)dst * NT + t] += w;
        __builtin_amdgcn_s_barrier();
    }
}

// ---------------- MFMA GEMM v2: LDS double-buffered via global_load_lds ----------------
// Tile 128x128, BK=32, 16 steps. LDS: A[2][8KB] @0, B[2][8KB] @16384.
// A LDS layout: row*64 + chunk*16 bytes, chunk XOR-swizzled with s(r)=(r&3)^((r>>2)&3)
// (swizzle applied on BOTH the pre-swizzled global source and the ds_read — rule #21).
__global__ __launch_bounds__(256, 4) void mfma_gemm_kernel(
    const unsigned short* __restrict__ ab, const unsigned short* __restrict__ bfrag,
    const float* __restrict__ s, const float* __restrict__ biasb,
    float* __restrict__ out, int nN) {
    __shared__ unsigned char lds[32768];
    int t = threadIdx.x;
    int w = t >> 6;
    int lane = t & 63;
    int wr = w >> 1, wc = w & 1;
    int ll = lane & 15;
    int ck = lane >> 4;
    long row0 = (long)blockIdx.x * 128;

    // ---- staging addresses (thread t stages LDS slot (row=t>>2, chunk=t&3)) ----
    int srow = t >> 2;                       // 0..63 (issue1 adds 64; swizzle unchanged)
    int clin = t & 3;
    int ssw = (srow & 3) ^ ((srow >> 2) & 3);
    int cg = clin ^ ssw;                     // inverse-swizzled source chunk
    long nodeA0 = row0 + srow;       if (nodeA0 >= nN) nodeA0 = nN - 1;
    long nodeA1 = row0 + 64 + srow;  if (nodeA1 >= nN) nodeA1 = nN - 1;
    const unsigned short* gA0 = ab + nodeA0 * 512 + cg * 8;
    const unsigned short* gA1 = ab + nodeA1 * 512 + cg * 8;
    const unsigned short* gB0 = bfrag + ((size_t)w * 64 + lane) * 8;
    const unsigned short* gB1 = bfrag + ((size_t)(4 + w) * 64 + lane) * 8;

#define STAGE(buf, st_) do {                                                            \
        unsigned char* la0 = lds + (buf) * 8192 + w * 1024;                             \
        unsigned char* la1 = lds + (buf) * 8192 + 4096 + w * 1024;                      \
        unsigned char* lb0 = lds + 16384 + (buf) * 8192 + w * 1024;                     \
        unsigned char* lb1 = lds + 16384 + (buf) * 8192 + 4096 + w * 1024;              \
        __builtin_amdgcn_global_load_lds((const __attribute__((address_space(1))) void*)(gA0 + (st_) * 32),            \
                                         (__attribute__((address_space(3))) void*)la0, 16, 0, 0);                      \
        __builtin_amdgcn_global_load_lds((const __attribute__((address_space(1))) void*)(gA1 + (st_) * 32),            \
                                         (__attribute__((address_space(3))) void*)la1, 16, 0, 0);                      \
        __builtin_amdgcn_global_load_lds((const __attribute__((address_space(1))) void*)(gB0 + (size_t)(st_) * 4096),  \
                                         (__attribute__((address_space(3))) void*)lb0, 16, 0, 0);                      \
        __builtin_amdgcn_global_load_lds((const __attribute__((address_space(1))) void*)(gB1 + (size_t)(st_) * 4096),  \
                                         (__attribute__((address_space(3))) void*)lb1, 16, 0, 0);                      \
    } while (0)

    // ---- read offsets ----
    int rsw = (ll & 3) ^ ((ll >> 2) & 3);    // same swizzle formula (row bits 0..3 = ll)
    int aoffBase = (wr * 64 + ll) * 64 + ((ck ^ rsw) * 16);
    int boffBase = 16384 + (wc * 4) * 1024 + lane * 16;

    f32x4 acc[4][4];
#pragma unroll
    for (int i = 0; i < 4; ++i)
#pragma unroll
        for (int j = 0; j < 4; ++j) acc[i][j] = (f32x4){0.f, 0.f, 0.f, 0.f};

    STAGE(0, 0);
    __syncthreads();

#pragma unroll 2
    for (int st = 0; st < 16; ++st) {
        int cur = st & 1;
        if (st < 15) STAGE(cur ^ 1, st + 1);
        const unsigned char* A = lds + cur * 8192;
        const unsigned char* B = lds + cur * 8192;
        bf16x8 aF[4], bF[4];
#pragma unroll
        for (int fr = 0; fr < 4; ++fr)
            aF[fr] = *(const bf16x8*)(A + aoffBase + fr * 1024);
#pragma unroll
        for (int fc = 0; fc < 4; ++fc)
            bF[fc] = *(const bf16x8*)(B + boffBase + fc * 1024);
#pragma unroll
        for (int fr = 0; fr < 4; ++fr)
#pragma unroll
            for (int fc = 0; fc < 4; ++fc)
                acc[fr][fc] = __builtin_amdgcn_mfma_f32_16x16x32_bf16(aF[fr], bF[fc], acc[fr][fc], 0, 0, 0);
        __syncthreads();
    }
#undef STAGE

    long wrow0 = row0 + wr * 64;
    int colb = wc * 64 + ll;
    float bb0[4], bb1[4], bb2[4], bs4[4];
#pragma unroll
    for (int fc = 0; fc < 4; ++fc) {
        int c = colb + fc * 16;
        bb0[fc] = biasb[c]; bb1[fc] = biasb[D + c];
        bb2[fc] = biasb[2 * D + c]; bs4[fc] = biasb[3 * D + c];
    }
    const float kInvSqrt2 = 0.70710678118654752440f;
#pragma unroll
    for (int fr = 0; fr < 4; ++fr) {
#pragma unroll
        for (int reg = 0; reg < 4; ++reg) {
            long row = wrow0 + fr * 16 + (lane >> 4) * 4 + reg;
            if (row >= nN) continue;
            float s0 = s[row * NT + 0];
            float s1 = s[row * NT + 1];
            float s2 = s[row * NT + 2];
#pragma unroll
            for (int fc = 0; fc < 4; ++fc) {
                float v = acc[fr][fc][reg] + bs4[fc] + s0 * bb0[fc] + s1 * bb1[fc] + s2 * bb2[fc];
                v = 0.5f * v * (1.f + erff(v * kInvSqrt2));
                out[row * D + colb + fc * 16] = v;
            }
        }
    }
}

// ================= FALLBACK PATH (small ws): f32 atomic scatter + f32 GEMM =================
__global__ __launch_bounds__(256) void scatterA_kernel(
    const float* __restrict__ x, const int* __restrict__ ei,
    const int* __restrict__ et, const float* __restrict__ ew,
    float* __restrict__ agg, float* __restrict__ s, int nE) {
    int gtid = blockIdx.x * blockDim.x + threadIdx.x;
    int wave = gtid >> 6;
    int lane = threadIdx.x & 63;
    int nw = (gridDim.x * blockDim.x) >> 6;
    for (int e = wave; e < nE; e += nw) {
        int src = ei[e];
        int dst = ei[nE + e];
        int t = et[e];
        float w = ew[e];
        float2 xv = *(const float2*)(x + (size_t)src * D + lane * 2);
        float* p = agg + (size_t)dst * (NT * D) + t * D + lane * 2;
        unsafeAtomicAdd(p, w * xv.x);
        unsafeAtomicAdd(p + 1, w * xv.y);
        if (lane == 0) unsafeAtomicAdd(s + (size_t)dst * NT + t, w);
    }
}

#define BM 64
#define BK 32
__global__ __launch_bounds__(256) void gemm_gelu_kernel(
    const float* __restrict__ x, const float* __restrict__ agg,
    const float* __restrict__ s, const float* __restrict__ wcat,
    const float* __restrict__ biasb, float* __restrict__ out, int nNodes) {
    __shared__ float As[BK][BM + 1];
    __shared__ float Bs[BK][D];

    int tx = threadIdx.x;
    int row0 = blockIdx.x * BM;
    int cg = tx & 31;
    int rg = tx >> 5;
    int lr = tx >> 3;
    int lc = (tx & 7) * 4;

    float acc[8][4];
#pragma unroll
    for (int i = 0; i < 8; ++i)
#pragma unroll
        for (int j = 0; j < 4; ++j) acc[i][j] = 0.f;

    for (int k0 = 0; k0 < KTOT; k0 += BK) {
        const float* srcBase;
        int strideA, koff;
        if (k0 < D) { srcBase = x; strideA = D; koff = k0; }
        else        { srcBase = agg; strideA = NT * D; koff = k0 - D; }
#pragma unroll
        for (int h = 0; h < 2; ++h) {
            int r = lr + h * 32;
            int node = row0 + r;
            if (node >= nNodes) node = nNodes - 1;
            float4 v = *(const float4*)(srcBase + (size_t)node * strideA + koff + lc);
            As[lc + 0][r] = v.x; As[lc + 1][r] = v.y;
            As[lc + 2][r] = v.z; As[lc + 3][r] = v.w;
        }
        {
            int br = tx >> 5;
            int bc = (tx & 31) * 4;
#pragma unroll
            for (int h = 0; h < 4; ++h) {
                int r = br + h * 8;
                *(float4*)(&Bs[r][bc]) = *(const float4*)(wcat + (size_t)(k0 + r) * D + bc);
            }
        }
        __syncthreads();
#pragma unroll
        for (int kk = 0; kk < BK; ++kk) {
            float4 b = *(const float4*)(&Bs[kk][cg * 4]);
            float a[8];
            *(float4*)(a)     = *(const float4*)(&As[kk][rg * 8]);
            *(float4*)(a + 4) = *(const float4*)(&As[kk][rg * 8 + 4]);
#pragma unroll
            for (int i = 0; i < 8; ++i) {
                acc[i][0] = fmaf(a[i], b.x, acc[i][0]);
                acc[i][1] = fmaf(a[i], b.y, acc[i][1]);
                acc[i][2] = fmaf(a[i], b.z, acc[i][2]);
                acc[i][3] = fmaf(a[i], b.w, acc[i][3]);
            }
        }
        __syncthreads();
    }

    int jc = cg * 4;
    float4 bb0 = *(const float4*)(biasb + 0 * D + jc);
    float4 bb1 = *(const float4*)(biasb + 1 * D + jc);
    float4 bb2 = *(const float4*)(biasb + 2 * D + jc);
    float4 bsv = *(const float4*)(biasb + NT * D + jc);
#pragma unroll
    for (int i = 0; i < 8; ++i) {
        int node = row0 + rg * 8 + i;
        if (node >= nNodes) break;
        float s0 = s[(size_t)node * NT + 0];
        float s1 = s[(size_t)node * NT + 1];
        float s2 = s[(size_t)node * NT + 2];
        float4 r;
        r.x = acc[i][0] + bsv.x + s0 * bb0.x + s1 * bb1.x + s2 * bb2.x;
        r.y = acc[i][1] + bsv.y + s0 * bb0.y + s1 * bb1.y + s2 * bb2.y;
        r.z = acc[i][2] + bsv.z + s0 * bb0.z + s1 * bb1.z + s2 * bb2.z;
        r.w = acc[i][3] + bsv.w + s0 * bb0.w + s1 * bb1.w + s2 * bb2.w;
        const float kInvSqrt2 = 0.70710678118654752440f;
        r.x = 0.5f * r.x * (1.f + erff(r.x * kInvSqrt2));
        r.y = 0.5f * r.y * (1.f + erff(r.y * kInvSqrt2));
        r.z = 0.5f * r.z * (1.f + erff(r.z * kInvSqrt2));
        r.w = 0.5f * r.w * (1.f + erff(r.w * kInvSqrt2));
        *(float4*)(out + (size_t)node * D + jc) = r;
    }
}

// ================= PATH C: zero-workspace fallback =================
__global__ __launch_bounds__(256) void selfmv_kernel(
    const float* __restrict__ x, const float* __restrict__ Ws,
    const float* __restrict__ bs, const float* __restrict__ attn,
    float* __restrict__ out, int nN) {
    float a0 = attn[0], a1 = attn[1], a2 = attn[2], a3 = attn[3];
    float m = fmaxf(fmaxf(a0, a1), fmaxf(a2, a3));
    float e3 = expf(a3 - m);
    float inv = 1.f / (expf(a0 - m) + expf(a1 - m) + expf(a2 - m) + e3);
    float at3 = e3 * inv;
    int wave = (blockIdx.x * blockDim.x + threadIdx.x) >> 6;
    int lane = threadIdx.x & 63;
    int nw = (gridDim.x * blockDim.x) >> 6;
    for (int n = wave; n < nN; n += nw) {
        float2 xr = *(const float2*)(x + (size_t)n * D + lane * 2);
        float acc0 = 0.f, acc1 = 0.f;
#pragma unroll
        for (int k = 0; k < D; ++k) {
            float xv = __shfl((k & 1) ? xr.y : xr.x, k >> 1);
            float2 wv = *(const float2*)(Ws + (size_t)k * D + lane * 2);
            acc0 = fmaf(xv, wv.x, acc0);
            acc1 = fmaf(xv, wv.y, acc1);
        }
        float2 r;
        r.x = at3 * (acc0 + bs[lane * 2]);
        r.y = at3 * (acc1 + bs[lane * 2 + 1]);
        *(float2*)(out + (size_t)n * D + lane * 2) = r;
    }
}

__global__ __launch_bounds__(256) void edgemv_kernel(
    const float* __restrict__ x, const int* __restrict__ ei,
    const int* __restrict__ et, const float* __restrict__ ew,
    const float* __restrict__ We, const float* __restrict__ be,
    const float* __restrict__ attn, float* __restrict__ out, int nE) {
    float a0 = attn[0], a1 = attn[1], a2 = attn[2], a3 = attn[3];
    float m = fmaxf(fmaxf(a0, a1), fmaxf(a2, a3));
    float e0 = expf(a0 - m), e1 = expf(a1 - m), e2 = expf(a2 - m), e3 = expf(a3 - m);
    float inv = 1.f / (e0 + e1 + e2 + e3);
    float at[NT] = {e0 * inv, e1 * inv, e2 * inv};
    int wave = (blockIdx.x * blockDim.x + threadIdx.x) >> 6;
    int lane = threadIdx.x & 63;
    int nw = (gridDim.x * blockDim.x) >> 6;
    for (int e = wave; e < nE; e += nw) {
        int src = ei[e];
        int dst = ei[nE + e];
        int t = et[e];
        float sc = ew[e] * at[t];
        const float* W = We + (size_t)t * D * D;
        float2 xr = *(const float2*)(x + (size_t)src * D + lane * 2);
        float acc0 = 0.f, acc1 = 0.f;
#pragma unroll
        for (int k = 0; k < D; ++k) {
            float xv = __shfl((k & 1) ? xr.y : xr.x, k >> 1);
            float2 wv = *(const float2*)(W + (size_t)k * D + lane * 2);
            acc0 = fmaf(xv, wv.x, acc0);
            acc1 = fmaf(xv, wv.y, acc1);
        }
        float* p = out + (size_t)dst * D + lane * 2;
        unsafeAtomicAdd(p,     sc * (acc0 + be[(size_t)t * D + lane * 2]));
        unsafeAtomicAdd(p + 1, sc * (acc1 + be[(size_t)t * D + lane * 2 + 1]));
    }
}

__global__ void gelu_kernel(float* __restrict__ p, long long n4) {
    long long i = (long long)blockIdx.x * blockDim.x + threadIdx.x;
    long long stride = (long long)gridDim.x * blockDim.x;
    const float kInvSqrt2 = 0.70710678118654752440f;
    for (; i < n4; i += stride) {
        float4 r = ((float4*)p)[i];
        r.x = 0.5f * r.x * (1.f + erff(r.x * kInvSqrt2));
        r.y = 0.5f * r.y * (1.f + erff(r.y * kInvSqrt2));
        r.z = 0.5f * r.z * (1.f + erff(r.z * kInvSqrt2));
        r.w = 0.5f * r.w * (1.f + erff(r.w * kInvSqrt2));
        ((float4*)p)[i] = r;
    }
}

extern "C" void kernel_launch(void* const* d_in, const int* in_sizes, int n_in,
                              void* d_out, int out_size, void* d_ws, size_t ws_size,
                              hipStream_t stream) {
    const float* x = (const float*)d_in[0];
    const int* ei = (const int*)d_in[1];      // int64 in reference -> int32 here
    const int* et = (const int*)d_in[2];
    const float* ew = (const float*)d_in[3];
    const float* W_edge = (const float*)d_in[4];
    const float* b_edge = (const float*)d_in[5];
    const float* W_self = (const float*)d_in[6];
    const float* b_self = (const float*)d_in[7];
    const float* attention = (const float*)d_in[8];
    float* out = (float*)d_out;

    const int nN = in_sizes[0] / D;   // 100000
    const int nE = in_sizes[2];       // 600000

    // ---- gather+MFMA path sizing ----
    int cap = 0;
    const int capCand[3] = {32, 24, 16};
    for (int ci = 0; ci < 3; ++ci) {
        int c = capCand[ci];
        size_t need = (size_t)nN * 1024            // ab bf16
                    + (size_t)nN * 12              // s
                    + (size_t)KTOT * D * 4         // wcat
                    + (size_t)KTOT * 4             // biasb
                    + 131072                       // bfrag
                    + 4 * ((size_t)nN + 2 + (size_t)nE)
                    + 8ull * nN * c;               // csr
        if (ws_size >= need) { cap = c; break; }
    }

    if (cap > 0) {
        unsigned short* ab = (unsigned short*)d_ws;            // nN*512
        float* sW = (float*)(ab + (size_t)nN * 512);           // nN*3
        float* wcat = sW + (size_t)nN * NT;                    // 512*128
        float* biasb = wcat + (size_t)KTOT * D;                // 512
        unsigned short* bfrag = (unsigned short*)(biasb + KTOT); // 65536
        int* deg = (int*)(bfrag + 65536);                      // nN
        int* ovfc = deg + nN;                                  // 2
        int* ovfl = ovfc + 2;                                  // nE
        int2* csr = (int2*)(ovfl + nE);                        // nN*cap

        hipLaunchKernelGGL(zeroi_kernel, dim3(128), dim3(256), 0, stream, deg, nN + 2);
        hipLaunchKernelGGL(prep_kernel, dim3(64), dim3(256), 0, stream,
                           W_edge, b_edge, W_self, b_self, attention, wcat, biasb, bfrag);
        hipLaunchKernelGGL(xcvt_kernel, dim3(2048), dim3(256), 0, stream, x, ab, nN);
        hipLaunchKernelGGL(fill_kernel, dim3((nE + 255) / 256), dim3(256), 0, stream,
                           ei, et, ew, deg, csr, ovfc, ovfl, nE, cap);
        hipLaunchKernelGGL(gatherb_kernel, dim3((nN + 15) / 16), dim3(256), 0, stream,
                           csr, deg, ab, sW, nN, cap);
        hipLaunchKernelGGL(ovf_fix_kernel, dim3(1), dim3(64), 0, stream,
                           ei, et, ew, ovfc, ovfl, ab, sW, nE);
        hipLaunchKernelGGL(mfma_gemm_kernel, dim3((nN + 127) / 128), dim3(256), 0, stream,
                           ab, bfrag, sW, biasb, out, nN);
        return;
    }

    const size_t baseFloats = (size_t)nN * NT * D + (size_t)nN * NT + (size_t)KTOT * D + KTOT;
    if (ws_size >= baseFloats * 4) {
        float* agg = (float*)d_ws;
        float* sW = agg + (size_t)nN * NT * D;
        float* wcat = sW + (size_t)nN * NT;
        float* biasb = wcat + (size_t)KTOT * D;
        long long zeroFloats = (long long)nN * (NT * D + NT);
        hipLaunchKernelGGL(zero_kernel, dim3(2048), dim3(256), 0, stream, agg, (zeroFloats + 3) / 4);
        hipLaunchKernelGGL(prep_kernel, dim3(64), dim3(256), 0, stream,
                           W_edge, b_edge, W_self, b_self, attention, wcat, biasb, (unsigned short*)wcat /*dummy; branch unreachable for this problem size*/);
        hipLaunchKernelGGL(scatterA_kernel, dim3(2048), dim3(256), 0, stream,
                           x, ei, et, ew, agg, sW, nE);
        hipLaunchKernelGGL(gemm_gelu_kernel, dim3((nN + BM - 1) / BM), dim3(256), 0, stream,
                           x, agg, sW, wcat, biasb, out, nN);
    } else {
        hipLaunchKernelGGL(selfmv_kernel, dim3(2048), dim3(256), 0, stream,
                           x, W_self, b_self, attention, out, nN);
        hipLaunchKernelGGL(edgemv_kernel, dim3(2048), dim3(256), 0, stream,
                           x, ei, et, ew, W_edge, b_edge, attention, out, nE);
        hipLaunchKernelGGL(gelu_kernel, dim3(2048), dim3(256), 0, stream,
                           out, (long long)nN * D / 4);
    }
}

// Round 7
// 124.689 us; speedup vs baseline: 6.1367x; 1.0477x over previous
//
#include <hip/hip_runtime.h>
#include <hip/hip_bf16.h>
#include <math.h>

#define D 128
#define NT 3
#define KTOT (D * (NT + 1))   // 512

typedef __attribute__((ext_vector_type(8))) __bf16 bf16x8;
typedef __attribute__((ext_vector_type(4))) float f32x4;

__device__ inline unsigned short f2bf(float f) {
    unsigned int u = __float_as_uint(f);
    unsigned int r = (u + 0x7FFFu + ((u >> 16) & 1u)) >> 16;
    return (unsigned short)r;
}

// ---------------- zero helper (fallback paths) ----------------
__global__ void zero_kernel(float* __restrict__ p, long long n4) {
    long long i = (long long)blockIdx.x * blockDim.x + threadIdx.x;
    long long stride = (long long)gridDim.x * blockDim.x;
    float4 z = make_float4(0.f, 0.f, 0.f, 0.f);
    for (; i < n4; i += stride) ((float4*)p)[i] = z;
}

// ---------------- prep (+ deg zero) ----------------
__global__ void prep_kernel(const float* __restrict__ W_edge, const float* __restrict__ b_edge,
                            const float* __restrict__ W_self, const float* __restrict__ b_self,
                            const float* __restrict__ attention,
                            float* __restrict__ wcat, float* __restrict__ biasb,
                            unsigned short* __restrict__ bfrag,
                            int* __restrict__ deg, int degN) {
    float a0 = attention[0], a1 = attention[1], a2 = attention[2], a3 = attention[3];
    float m = fmaxf(fmaxf(a0, a1), fmaxf(a2, a3));
    float e0 = expf(a0 - m), e1 = expf(a1 - m), e2 = expf(a2 - m), e3 = expf(a3 - m);
    float inv = 1.f / (e0 + e1 + e2 + e3);
    float at[4] = {e0 * inv, e1 * inv, e2 * inv, e3 * inv};

    int idx0 = blockIdx.x * blockDim.x + threadIdx.x;
    int stride = gridDim.x * blockDim.x;
    if (deg) {
        for (int i = idx0; i < degN; i += stride) deg[i] = 0;
    }
    for (int i = idx0; i < KTOT * D; i += stride) {
        int k = i >> 7, j = i & (D - 1);
        float v;
        if (k < D) {
            v = at[NT] * W_self[k * D + j];
        } else {
            int t = (k - D) >> 7;
            int kk = (k - D) & (D - 1);
            v = at[t] * W_edge[(t * D + kk) * D + j];
        }
        wcat[i] = v;
    }
    for (int i = idx0; i < KTOT; i += stride) {
        if (i < NT * D) {
            int t = i >> 7, j = i & (D - 1);
            biasb[i] = at[t] * b_edge[t * D + j];
        } else {
            biasb[i] = at[NT] * b_self[i - NT * D];
        }
    }
    // bfrag: [(step*8+cf)*64+lane]*8 ; B[k][col], col=cf*16+(l&15), k=step*32+(l>>4)*8+j
    for (int i = idx0; i < 16 * 8 * 64; i += stride) {
        int l = i & 63;
        int cf = (i >> 6) & 7;
        int step = i >> 9;
        int col = cf * 16 + (l & 15);
        int kb = step * 32 + ((l >> 4) * 8);
#pragma unroll
        for (int j = 0; j < 8; ++j) {
            int k = kb + j;
            float v;
            if (k < D) {
                v = at[NT] * W_self[k * D + col];
            } else {
                int t = (k - D) >> 7;
                int kk = (k - D) & (D - 1);
                v = at[t] * W_edge[(t * D + kk) * D + col];
            }
            bfrag[(size_t)i * 8 + j] = f2bf(v);
        }
    }
}

// ---------------- combined: x->bf16 convert (blocks < XB) + edge bucketing (blocks >= XB) ----------------
__global__ __launch_bounds__(256) void xcvt_fill_kernel(
    const float* __restrict__ x, unsigned short* __restrict__ ab, int nN,
    const int* __restrict__ ei, const int* __restrict__ et, const float* __restrict__ ew,
    int* __restrict__ deg, int2* __restrict__ csr, int* __restrict__ ovfcnt,
    int* __restrict__ ovflist, int nE, int cap, int XB) {
    int b = blockIdx.x;
    if (b < XB) {
        int i = b * 256 + threadIdx.x;
        int total = nN * (D / 4);
        int stride = XB * 256;
        for (; i < total; i += stride) {
            int n = i >> 5;
            int c4 = (i & 31) * 4;
            float4 v = *(const float4*)(x + (size_t)n * D + c4);
            ushort4 o;
            o.x = f2bf(v.x); o.y = f2bf(v.y); o.z = f2bf(v.z); o.w = f2bf(v.w);
            *(ushort4*)(ab + (size_t)n * 512 + c4) = o;
        }
    } else {
        int e = (b - XB) * 256 + threadIdx.x;
        if (e >= nE) return;
        int dst = ei[nE + e];
        int pos = atomicAdd(deg + dst, 1);
        if (pos < cap) {
            int src = ei[e];
            int t = et[e];
            csr[(size_t)dst * cap + pos] = make_int2(src | (t << 20), __float_as_int(ew[e]));
        } else {
            int o = atomicAdd(ovfcnt, 1);
            ovflist[o] = e;
        }
    }
}

// ---------------- gather: 4 nodes/wave (16 lanes each), reg-prefetched metas, 2x unroll ----------------
__global__ __launch_bounds__(256) void gatherb_kernel(
    const int2* __restrict__ csr, const int* __restrict__ deg,
    unsigned short* __restrict__ ab, float* __restrict__ s, int nN, int cap) {
    int wid = (blockIdx.x * blockDim.x + threadIdx.x) >> 6;
    int lane = threadIdx.x & 63;
    int gl = lane & 15;
    int base = lane & 48;
    int node = wid * 4 + (lane >> 4);
    int nclamp = (node < nN) ? node : (nN - 1);
    int dg = deg[nclamp];
    if (dg > cap) dg = cap;
    if (node >= nN) dg = 0;
    const int2* c = csr + (size_t)nclamp * cap;
    int2 mA = (gl < dg) ? c[gl] : make_int2(0, 0);
    int2 mB = (gl + 16 < dg) ? c[gl + 16] : make_int2(0, 0);

    float ac0[8], ac1[8], ac2[8];
#pragma unroll
    for (int j = 0; j < 8; ++j) { ac0[j] = 0.f; ac1[j] = 0.f; ac2[j] = 0.f; }
    float sw0 = 0.f, sw1 = 0.f, sw2 = 0.f;

    for (int i = 0; i < dg; i += 2) {
        int slA = base + (i & 15);
        int exA = __shfl((i < 16) ? mA.x : mB.x, slA);
        int ewA = __shfl((i < 16) ? mA.y : mB.y, slA);
        int srcA = exA & 0xFFFFF;
        if (srcA >= nN) srcA = 0;
        float wA = __int_as_float(ewA);
        int tA = (exA >> 20) & 3;
        bool actB = (i + 1 < dg);
        int slB = base + ((i + 1) & 15);
        int exB = __shfl((i + 1 < 16) ? mA.x : mB.x, slB);
        int ewB = __shfl((i + 1 < 16) ? mA.y : mB.y, slB);
        int srcB = exB & 0xFFFFF;
        if (!actB || srcB >= nN) srcB = 0;
        float wB = actB ? __int_as_float(ewB) : 0.f;
        int tB = (exB >> 20) & 3;

        uint4 xa = *(const uint4*)(ab + (size_t)srcA * 512 + gl * 8);
        uint4 xb = *(const uint4*)(ab + (size_t)srcB * 512 + gl * 8);

        float wA0 = (tA == 0) ? wA : 0.f;
        float wA1 = (tA == 1) ? wA : 0.f;
        float wA2 = (tA == 2) ? wA : 0.f;
        float wB0 = (tB == 0) ? wB : 0.f;
        float wB1 = (tB == 1) ? wB : 0.f;
        float wB2 = (tB == 2) ? wB : 0.f;
        sw0 += wA0 + wB0; sw1 += wA1 + wB1; sw2 += wA2 + wB2;

        float f0, f1;
#define ACCUM(u, j0, j1, w0_, w1_, w2_)                                   \
        f0 = __uint_as_float((u) << 16);                                  \
        f1 = __uint_as_float((u) & 0xFFFF0000u);                          \
        ac0[j0] = fmaf(w0_, f0, ac0[j0]); ac0[j1] = fmaf(w0_, f1, ac0[j1]); \
        ac1[j0] = fmaf(w1_, f0, ac1[j0]); ac1[j1] = fmaf(w1_, f1, ac1[j1]); \
        ac2[j0] = fmaf(w2_, f0, ac2[j0]); ac2[j1] = fmaf(w2_, f1, ac2[j1]);

        ACCUM(xa.x, 0, 1, wA0, wA1, wA2)
        ACCUM(xa.y, 2, 3, wA0, wA1, wA2)
        ACCUM(xa.z, 4, 5, wA0, wA1, wA2)
        ACCUM(xa.w, 6, 7, wA0, wA1, wA2)
        ACCUM(xb.x, 0, 1, wB0, wB1, wB2)
        ACCUM(xb.y, 2, 3, wB0, wB1, wB2)
        ACCUM(xb.z, 4, 5, wB0, wB1, wB2)
        ACCUM(xb.w, 6, 7, wB0, wB1, wB2)
#undef ACCUM
    }

    if (node < nN) {
        unsigned short* ap = ab + (size_t)node * 512 + D;
        uint4 o;
#define PACK(arr)                                                           \
        o.x = (unsigned int)f2bf(arr[0]) | ((unsigned int)f2bf(arr[1]) << 16); \
        o.y = (unsigned int)f2bf(arr[2]) | ((unsigned int)f2bf(arr[3]) << 16); \
        o.z = (unsigned int)f2bf(arr[4]) | ((unsigned int)f2bf(arr[5]) << 16); \
        o.w = (unsigned int)f2bf(arr[6]) | ((unsigned int)f2bf(arr[7]) << 16);
        PACK(ac0) *(uint4*)(ap + 0 * D + gl * 8) = o;
        PACK(ac1) *(uint4*)(ap + 1 * D + gl * 8) = o;
        PACK(ac2) *(uint4*)(ap + 2 * D + gl * 8) = o;
#undef PACK
        if (gl < 3) {
            float sv = (gl == 0) ? sw0 : ((gl == 1) ? sw1 : sw2);
            s[(size_t)node * NT + gl] = sv;
        }
    }
}

// ---------------- overflow fixup ----------------
__global__ __launch_bounds__(64) void ovf_fix_kernel(
    const int* __restrict__ ei, const int* __restrict__ et, const float* __restrict__ ew,
    const int* __restrict__ ovfcnt, const int* __restrict__ ovflist,
    unsigned short* __restrict__ ab, float* __restrict__ s, int nE) {
    int cnt = *ovfcnt;
    int lane = threadIdx.x;
    for (int i = 0; i < cnt; ++i) {
        int e = ovflist[i];
        int src = ei[e], dst = ei[nE + e], t = et[e];
        float w = ew[e];
        unsigned int xu = *(const unsigned int*)(ab + (size_t)src * 512 + lane * 2);
        float x0 = __uint_as_float(xu << 16);
        float x1 = __uint_as_float(xu & 0xFFFF0000u);
        unsigned short* p = ab + (size_t)dst * 512 + D + t * D + lane * 2;
        unsigned int au = *(unsigned int*)p;
        float v0 = __uint_as_float(au << 16) + w * x0;
        float v1 = __uint_as_float(au & 0xFFFF0000u) + w * x1;
        *(unsigned int*)p = (unsigned int)f2bf(v0) | ((unsigned int)f2bf(v1) << 16);
        if (lane == 0) s[(size_t)dst * NT + t] += w;
        __builtin_amdgcn_s_barrier();
    }
}

// ---------------- MFMA GEMM v3: 64x128 tile, LDS double-buffered, 1563 blocks ----------------
// LDS: A[2][4KB] @0, B[2][8KB] @8192. Total 24576.
// A layout: row*64 + chunk*16, chunk XOR-swizzled s(r)=(r&3)^((r>>2)&3) (both sides — rule #21).
__global__ __launch_bounds__(256, 4) void mfma_gemm_kernel(
    const unsigned short* __restrict__ ab, const unsigned short* __restrict__ bfrag,
    const float* __restrict__ s, const float* __restrict__ biasb,
    float* __restrict__ out, int nN) {
    __shared__ unsigned char lds[24576];
    int t = threadIdx.x;
    int w = t >> 6;
    int lane = t & 63;
    int wr = w >> 1, wc = w & 1;
    int ll = lane & 15;
    int ck = lane >> 4;
    long row0 = (long)blockIdx.x * 64;

    // staging: thread t -> A slot (row=t>>2 in [0,64), chunk=t&3)
    int srow = t >> 2;
    int clin = t & 3;
    int ssw = (srow & 3) ^ ((srow >> 2) & 3);
    int cg = clin ^ ssw;
    long nodeA = row0 + srow; if (nodeA >= nN) nodeA = nN - 1;
    const unsigned short* gA = ab + nodeA * 512 + cg * 8;
    const unsigned short* gB0 = bfrag + ((size_t)w * 64 + lane) * 8;
    const unsigned short* gB1 = bfrag + ((size_t)(4 + w) * 64 + lane) * 8;

#define STAGE(buf, st_) do {                                                            \
        unsigned char* la  = lds + (buf) * 4096 + w * 1024;                             \
        unsigned char* lb0 = lds + 8192 + (buf) * 8192 + w * 1024;                      \
        unsigned char* lb1 = lds + 8192 + (buf) * 8192 + 4096 + w * 1024;               \
        __builtin_amdgcn_global_load_lds((const __attribute__((address_space(1))) void*)(gA + (st_) * 32),             \
                                         (__attribute__((address_space(3))) void*)la, 16, 0, 0);                       \
        __builtin_amdgcn_global_load_lds((const __attribute__((address_space(1))) void*)(gB0 + (size_t)(st_) * 4096),  \
                                         (__attribute__((address_space(3))) void*)lb0, 16, 0, 0);                      \
        __builtin_amdgcn_global_load_lds((const __attribute__((address_space(1))) void*)(gB1 + (size_t)(st_) * 4096),  \
                                         (__attribute__((address_space(3))) void*)lb1, 16, 0, 0);                      \
    } while (0)

    // read offsets
    int rsw = (ll & 3) ^ ((ll >> 2) & 3);
    int aoffBase = (wr * 32 + ll) * 64 + ((ck ^ rsw) * 16);   // + fr*16*64 per frag
    int boffBase = 8192 + wc * 4096 + lane * 16;              // + fc*1024 per frag (+cur*8192)

    f32x4 acc[2][4];
#pragma unroll
    for (int i = 0; i < 2; ++i)
#pragma unroll
        for (int j = 0; j < 4; ++j) acc[i][j] = (f32x4){0.f, 0.f, 0.f, 0.f};

    STAGE(0, 0);
    __syncthreads();

#pragma unroll 2
    for (int st = 0; st < 16; ++st) {
        int cur = st & 1;
        if (st < 15) STAGE(cur ^ 1, st + 1);
        const unsigned char* A = lds + cur * 4096;
        const unsigned char* B = lds + cur * 8192;
        bf16x8 aF[2], bF[4];
#pragma unroll
        for (int fr = 0; fr < 2; ++fr)
            aF[fr] = *(const bf16x8*)(A + aoffBase + fr * 1024);
#pragma unroll
        for (int fc = 0; fc < 4; ++fc)
            bF[fc] = *(const bf16x8*)(B + boffBase + fc * 1024);
#pragma unroll
        for (int fr = 0; fr < 2; ++fr)
#pragma unroll
            for (int fc = 0; fc < 4; ++fc)
                acc[fr][fc] = __builtin_amdgcn_mfma_f32_16x16x32_bf16(aF[fr], bF[fc], acc[fr][fc], 0, 0, 0);
        __syncthreads();
    }
#undef STAGE

    long wrow0 = row0 + wr * 32;
    int colb = wc * 64 + ll;
    float bb0[4], bb1[4], bb2[4], bs4[4];
#pragma unroll
    for (int fc = 0; fc < 4; ++fc) {
        int c = colb + fc * 16;
        bb0[fc] = biasb[c]; bb1[fc] = biasb[D + c];
        bb2[fc] = biasb[2 * D + c]; bs4[fc] = biasb[3 * D + c];
    }
    const float kInvSqrt2 = 0.70710678118654752440f;
#pragma unroll
    for (int fr = 0; fr < 2; ++fr) {
#pragma unroll
        for (int reg = 0; reg < 4; ++reg) {
            long row = wrow0 + fr * 16 + (lane >> 4) * 4 + reg;
            if (row >= nN) continue;
            float s0 = s[row * NT + 0];
            float s1 = s[row * NT + 1];
            float s2 = s[row * NT + 2];
#pragma unroll
            for (int fc = 0; fc < 4; ++fc) {
                float v = acc[fr][fc][reg] + bs4[fc] + s0 * bb0[fc] + s1 * bb1[fc] + s2 * bb2[fc];
                v = 0.5f * v * (1.f + erff(v * kInvSqrt2));
                out[row * D + colb + fc * 16] = v;
            }
        }
    }
}

// ================= FALLBACK PATH (small ws): f32 atomic scatter + f32 GEMM =================
__global__ __launch_bounds__(256) void scatterA_kernel(
    const float* __restrict__ x, const int* __restrict__ ei,
    const int* __restrict__ et, const float* __restrict__ ew,
    float* __restrict__ agg, float* __restrict__ s, int nE) {
    int gtid = blockIdx.x * blockDim.x + threadIdx.x;
    int wave = gtid >> 6;
    int lane = threadIdx.x & 63;
    int nw = (gridDim.x * blockDim.x) >> 6;
    for (int e = wave; e < nE; e += nw) {
        int src = ei[e];
        int dst = ei[nE + e];
        int t = et[e];
        float w = ew[e];
        float2 xv = *(const float2*)(x + (size_t)src * D + lane * 2);
        float* p = agg + (size_t)dst * (NT * D) + t * D + lane * 2;
        unsafeAtomicAdd(p, w * xv.x);
        unsafeAtomicAdd(p + 1, w * xv.y);
        if (lane == 0) unsafeAtomicAdd(s + (size_t)dst * NT + t, w);
    }
}

#define BM 64
#define BK 32
__global__ __launch_bounds__(256) void gemm_gelu_kernel(
    const float* __restrict__ x, const float* __restrict__ agg,
    const float* __restrict__ s, const float* __restrict__ wcat,
    const float* __restrict__ biasb, float* __restrict__ out, int nNodes) {
    __shared__ float As[BK][BM + 1];
    __shared__ float Bs[BK][D];

    int tx = threadIdx.x;
    int row0 = blockIdx.x * BM;
    int cg = tx & 31;
    int rg = tx >> 5;
    int lr = tx >> 3;
    int lc = (tx & 7) * 4;

    float acc[8][4];
#pragma unroll
    for (int i = 0; i < 8; ++i)
#pragma unroll
        for (int j = 0; j < 4; ++j) acc[i][j] = 0.f;

    for (int k0 = 0; k0 < KTOT; k0 += BK) {
        const float* srcBase;
        int strideA, koff;
        if (k0 < D) { srcBase = x; strideA = D; koff = k0; }
        else        { srcBase = agg; strideA = NT * D; koff = k0 - D; }
#pragma unroll
        for (int h = 0; h < 2; ++h) {
            int r = lr + h * 32;
            int node = row0 + r;
            if (node >= nNodes) node = nNodes - 1;
            float4 v = *(const float4*)(srcBase + (size_t)node * strideA + koff + lc);
            As[lc + 0][r] = v.x; As[lc + 1][r] = v.y;
            As[lc + 2][r] = v.z; As[lc + 3][r] = v.w;
        }
        {
            int br = tx >> 5;
            int bc = (tx & 31) * 4;
#pragma unroll
            for (int h = 0; h < 4; ++h) {
                int r = br + h * 8;
                *(float4*)(&Bs[r][bc]) = *(const float4*)(wcat + (size_t)(k0 + r) * D + bc);
            }
        }
        __syncthreads();
#pragma unroll
        for (int kk = 0; kk < BK; ++kk) {
            float4 b = *(const float4*)(&Bs[kk][cg * 4]);
            float a[8];
            *(float4*)(a)     = *(const float4*)(&As[kk][rg * 8]);
            *(float4*)(a + 4) = *(const float4*)(&As[kk][rg * 8 + 4]);
#pragma unroll
            for (int i = 0; i < 8; ++i) {
                acc[i][0] = fmaf(a[i], b.x, acc[i][0]);
                acc[i][1] = fmaf(a[i], b.y, acc[i][1]);
                acc[i][2] = fmaf(a[i], b.z, acc[i][2]);
                acc[i][3] = fmaf(a[i], b.w, acc[i][3]);
            }
        }
        __syncthreads();
    }

    int jc = cg * 4;
    float4 bb0 = *(const float4*)(biasb + 0 * D + jc);
    float4 bb1 = *(const float4*)(biasb + 1 * D + jc);
    float4 bb2 = *(const float4*)(biasb + 2 * D + jc);
    float4 bsv = *(const float4*)(biasb + NT * D + jc);
#pragma unroll
    for (int i = 0; i < 8; ++i) {
        int node = row0 + rg * 8 + i;
        if (node >= nNodes) break;
        float s0 = s[(size_t)node * NT + 0];
        float s1 = s[(size_t)node * NT + 1];
        float s2 = s[(size_t)node * NT + 2];
        float4 r;
        r.x = acc[i][0] + bsv.x + s0 * bb0.x + s1 * bb1.x + s2 * bb2.x;
        r.y = acc[i][1] + bsv.y + s0 * bb0.y + s1 * bb1.y + s2 * bb2.y;
        r.z = acc[i][2] + bsv.z + s0 * bb0.z + s1 * bb1.z + s2 * bb2.z;
        r.w = acc[i][3] + bsv.w + s0 * bb0.w + s1 * bb1.w + s2 * bb2.w;
        const float kInvSqrt2 = 0.70710678118654752440f;
        r.x = 0.5f * r.x * (1.f + erff(r.x * kInvSqrt2));
        r.y = 0.5f * r.y * (1.f + erff(r.y * kInvSqrt2));
        r.z = 0.5f * r.z * (1.f + erff(r.z * kInvSqrt2));
        r.w = 0.5f * r.w * (1.f + erff(r.w * kInvSqrt2));
        *(float4*)(out + (size_t)node * D + jc) = r;
    }
}

// ================= PATH C: zero-workspace fallback =================
__global__ __launch_bounds__(256) void selfmv_kernel(
    const float* __restrict__ x, const float* __restrict__ Ws,
    const float* __restrict__ bs, const float* __restrict__ attn,
    float* __restrict__ out, int nN) {
    float a0 = attn[0], a1 = attn[1], a2 = attn[2], a3 = attn[3];
    float m = fmaxf(fmaxf(a0, a1), fmaxf(a2, a3));
    float e3 = expf(a3 - m);
    float inv = 1.f / (expf(a0 - m) + expf(a1 - m) + expf(a2 - m) + e3);
    float at3 = e3 * inv;
    int wave = (blockIdx.x * blockDim.x + threadIdx.x) >> 6;
    int lane = threadIdx.x & 63;
    int nw = (gridDim.x * blockDim.x) >> 6;
    for (int n = wave; n < nN; n += nw) {
        float2 xr = *(const float2*)(x + (size_t)n * D + lane * 2);
        float acc0 = 0.f, acc1 = 0.f;
#pragma unroll
        for (int k = 0; k < D; ++k) {
            float xv = __shfl((k & 1) ? xr.y : xr.x, k >> 1);
            float2 wv = *(const float2*)(Ws + (size_t)k * D + lane * 2);
            acc0 = fmaf(xv, wv.x, acc0);
            acc1 = fmaf(xv, wv.y, acc1);
        }
        float2 r;
        r.x = at3 * (acc0 + bs[lane * 2]);
        r.y = at3 * (acc1 + bs[lane * 2 + 1]);
        *(float2*)(out + (size_t)n * D + lane * 2) = r;
    }
}

__global__ __launch_bounds__(256) void edgemv_kernel(
    const float* __restrict__ x, const int* __restrict__ ei,
    const int* __restrict__ et, const float* __restrict__ ew,
    const float* __restrict__ We, const float* __restrict__ be,
    const float* __restrict__ attn, float* __restrict__ out, int nE) {
    float a0 = attn[0], a1 = attn[1], a2 = attn[2], a3 = attn[3];
    float m = fmaxf(fmaxf(a0, a1), fmaxf(a2, a3));
    float e0 = expf(a0 - m), e1 = expf(a1 - m), e2 = expf(a2 - m), e3 = expf(a3 - m);
    float inv = 1.f / (e0 + e1 + e2 + e3);
    float at[NT] = {e0 * inv, e1 * inv, e2 * inv};
    int wave = (blockIdx.x * blockDim.x + threadIdx.x) >> 6;
    int lane = threadIdx.x & 63;
    int nw = (gridDim.x * blockDim.x) >> 6;
    for (int e = wave; e < nE; e += nw) {
        int src = ei[e];
        int dst = ei[nE + e];
        int t = et[e];
        float sc = ew[e] * at[t];
        const float* W = We + (size_t)t * D * D;
        float2 xr = *(const float2*)(x + (size_t)src * D + lane * 2);
        float acc0 = 0.f, acc1 = 0.f;
#pragma unroll
        for (int k = 0; k < D; ++k) {
            float xv = __shfl((k & 1) ? xr.y : xr.x, k >> 1);
            float2 wv = *(const float2*)(W + (size_t)k * D + lane * 2);
            acc0 = fmaf(xv, wv.x, acc0);
            acc1 = fmaf(xv, wv.y, acc1);
        }
        float* p = out + (size_t)dst * D + lane * 2;
        unsafeAtomicAdd(p,     sc * (acc0 + be[(size_t)t * D + lane * 2]));
        unsafeAtomicAdd(p + 1, sc * (acc1 + be[(size_t)t * D + lane * 2 + 1]));
    }
}

__global__ void gelu_kernel(float* __restrict__ p, long long n4) {
    long long i = (long long)blockIdx.x * blockDim.x + threadIdx.x;
    long long stride = (long long)gridDim.x * blockDim.x;
    const float kInvSqrt2 = 0.70710678118654752440f;
    for (; i < n4; i += stride) {
        float4 r = ((float4*)p)[i];
        r.x = 0.5f * r.x * (1.f + erff(r.x * kInvSqrt2));
        r.y = 0.5f * r.y * (1.f + erff(r.y * kInvSqrt2));
        r.z = 0.5f * r.z * (1.f + erff(r.z * kInvSqrt2));
        r.w = 0.5f * r.w * (1.f + erff(r.w * kInvSqrt2));
        ((float4*)p)[i] = r;
    }
}

extern "C" void kernel_launch(void* const* d_in, const int* in_sizes, int n_in,
                              void* d_out, int out_size, void* d_ws, size_t ws_size,
                              hipStream_t stream) {
    const float* x = (const float*)d_in[0];
    const int* ei = (const int*)d_in[1];      // int64 in reference -> int32 here
    const int* et = (const int*)d_in[2];
    const float* ew = (const float*)d_in[3];
    const float* W_edge = (const float*)d_in[4];
    const float* b_edge = (const float*)d_in[5];
    const float* W_self = (const float*)d_in[6];
    const float* b_self = (const float*)d_in[7];
    const float* attention = (const float*)d_in[8];
    float* out = (float*)d_out;

    const int nN = in_sizes[0] / D;   // 100000
    const int nE = in_sizes[2];       // 600000

    // ---- gather+MFMA path sizing ----
    int cap = 0;
    const int capCand[3] = {32, 24, 16};
    for (int ci = 0; ci < 3; ++ci) {
        int c = capCand[ci];
        size_t need = (size_t)nN * 1024            // ab bf16
                    + (size_t)nN * 12              // s
                    + (size_t)KTOT * D * 4         // wcat
                    + (size_t)KTOT * 4             // biasb
                    + 131072                       // bfrag
                    + 4 * ((size_t)nN + 2 + (size_t)nE)
                    + 8ull * nN * c;               // csr
        if (ws_size >= need) { cap = c; break; }
    }

    if (cap > 0) {
        unsigned short* ab = (unsigned short*)d_ws;            // nN*512
        float* sW = (float*)(ab + (size_t)nN * 512);           // nN*3
        float* wcat = sW + (size_t)nN * NT;                    // 512*128
        float* biasb = wcat + (size_t)KTOT * D;                // 512
        unsigned short* bfrag = (unsigned short*)(biasb + KTOT); // 65536
        int* deg = (int*)(bfrag + 65536);                      // nN
        int* ovfc = deg + nN;                                  // 2
        int* ovfl = ovfc + 2;                                  // nE
        int2* csr = (int2*)(ovfl + nE);                        // nN*cap

        hipLaunchKernelGGL(prep_kernel, dim3(64), dim3(256), 0, stream,
                           W_edge, b_edge, W_self, b_self, attention, wcat, biasb, bfrag,
                           deg, nN + 2);
        const int XB = 512;
        const int FB = (nE + 255) / 256;
        hipLaunchKernelGGL(xcvt_fill_kernel, dim3(XB + FB), dim3(256), 0, stream,
                           x, ab, nN, ei, et, ew, deg, csr, ovfc, ovfl, nE, cap, XB);
        hipLaunchKernelGGL(gatherb_kernel, dim3((nN + 15) / 16), dim3(256), 0, stream,
                           csr, deg, ab, sW, nN, cap);
        hipLaunchKernelGGL(ovf_fix_kernel, dim3(1), dim3(64), 0, stream,
                           ei, et, ew, ovfc, ovfl, ab, sW, nE);
        hipLaunchKernelGGL(mfma_gemm_kernel, dim3((nN + 63) / 64), dim3(256), 0, stream,
                           ab, bfrag, sW, biasb, out, nN);
        return;
    }

    const size_t baseFloats = (size_t)nN * NT * D + (size_t)nN * NT + (size_t)KTOT * D + KTOT;
    if (ws_size >= baseFloats * 4) {
        float* agg = (float*)d_ws;
        float* sW = agg + (size_t)nN * NT * D;
        float* wcat = sW + (size_t)nN * NT;
        float* biasb = wcat + (size_t)KTOT * D;
        long long zeroFloats = (long long)nN * (NT * D + NT);
        hipLaunchKernelGGL(zero_kernel, dim3(2048), dim3(256), 0, stream, agg, (zeroFloats + 3) / 4);
        hipLaunchKernelGGL(prep_kernel, dim3(64), dim3(256), 0, stream,
                           W_edge, b_edge, W_self, b_self, attention, wcat, biasb,
                           (unsigned short*)wcat /*dummy; branch unreachable at this size*/,
                           (int*)nullptr, 0);
        hipLaunchKernelGGL(scatterA_kernel, dim3(2048), dim3(256), 0, stream,
                           x, ei, et, ew, agg, sW, nE);
        hipLaunchKernelGGL(gemm_gelu_kernel, dim3((nN + BM - 1) / BM), dim3(256), 0, stream,
                           x, agg, sW, wcat, biasb, out, nN);
    } else {
        hipLaunchKernelGGL(selfmv_kernel, dim3(2048), dim3(256), 0, stream,
                           x, W_self, b_self, attention, out, nN);
        hipLaunchKernelGGL(edgemv_kernel, dim3(2048), dim3(256), 0, stream,
                           x, ei, et, ew, W_edge, b_edge, attention, out, nE);
        hipLaunchKernelGGL(gelu_kernel, dim3(2048), dim3(256), 0, stream,
                           out, (long long)nN * D / 4);
    }
}

// Round 8
// 123.467 us; speedup vs baseline: 6.1974x; 1.0099x over previous
//
#include <hip/hip_runtime.h>
#include <hip/hip_bf16.h>
#include <math.h>

#define D 128
#define NT 3
#define KTOT (D * (NT + 1))   // 512
#define TM 32                 // fused tile rows

typedef __attribute__((ext_vector_type(8))) __bf16 bf16x8;
typedef __attribute__((ext_vector_type(4))) float f32x4;

__device__ inline unsigned short f2bf(float f) {
    unsigned int u = __float_as_uint(f);
    unsigned int r = (u + 0x7FFFu + ((u >> 16) & 1u)) >> 16;
    return (unsigned short)r;
}
__device__ inline float bf2f(unsigned int hi16_as_low) {
    return __uint_as_float(hi16_as_low << 16);
}

// ---------------- zero helper (fallback path) ----------------
__global__ void zero_kernel(float* __restrict__ p, long long n4) {
    long long i = (long long)blockIdx.x * blockDim.x + threadIdx.x;
    long long stride = (long long)gridDim.x * blockDim.x;
    float4 z = make_float4(0.f, 0.f, 0.f, 0.f);
    for (; i < n4; i += stride) ((float4*)p)[i] = z;
}

// ---------------- prep: softmax(attention) -> wcat, biasb, bfrag; zero deg ----------------
__global__ void prep_kernel(const float* __restrict__ W_edge, const float* __restrict__ b_edge,
                            const float* __restrict__ W_self, const float* __restrict__ b_self,
                            const float* __restrict__ attention,
                            float* __restrict__ wcat, float* __restrict__ biasb,
                            unsigned short* __restrict__ bfrag,
                            int* __restrict__ deg, int degN) {
    float a0 = attention[0], a1 = attention[1], a2 = attention[2], a3 = attention[3];
    float m = fmaxf(fmaxf(a0, a1), fmaxf(a2, a3));
    float e0 = expf(a0 - m), e1 = expf(a1 - m), e2 = expf(a2 - m), e3 = expf(a3 - m);
    float inv = 1.f / (e0 + e1 + e2 + e3);
    float at[4] = {e0 * inv, e1 * inv, e2 * inv, e3 * inv};

    int idx0 = blockIdx.x * blockDim.x + threadIdx.x;
    int stride = gridDim.x * blockDim.x;
    if (deg) {
        for (int i = idx0; i < degN; i += stride) deg[i] = 0;
    }
    for (int i = idx0; i < KTOT * D; i += stride) {
        int k = i >> 7, j = i & (D - 1);
        float v;
        if (k < D) {
            v = at[NT] * W_self[k * D + j];
        } else {
            int t = (k - D) >> 7;
            int kk = (k - D) & (D - 1);
            v = at[t] * W_edge[(t * D + kk) * D + j];
        }
        wcat[i] = v;
    }
    for (int i = idx0; i < KTOT; i += stride) {
        if (i < NT * D) {
            int t = i >> 7, j = i & (D - 1);
            biasb[i] = at[t] * b_edge[t * D + j];
        } else {
            biasb[i] = at[NT] * b_self[i - NT * D];
        }
    }
    if (bfrag) {
        // bfrag: [(step*8+cf)*64+lane]*8 ; B[k][col], col=cf*16+(l&15), k=step*32+(l>>4)*8+j
        for (int i = idx0; i < 16 * 8 * 64; i += stride) {
            int l = i & 63;
            int cf = (i >> 6) & 7;
            int step = i >> 9;
            int col = cf * 16 + (l & 15);
            int kb = step * 32 + ((l >> 4) * 8);
#pragma unroll
            for (int j = 0; j < 8; ++j) {
                int k = kb + j;
                float v;
                if (k < D) {
                    v = at[NT] * W_self[k * D + col];
                } else {
                    int t = (k - D) >> 7;
                    int kk = (k - D) & (D - 1);
                    v = at[t] * W_edge[(t * D + kk) * D + col];
                }
                bfrag[(size_t)i * 8 + j] = f2bf(v);
            }
        }
    }
}

// ---------------- fill: bucket edges by dst ----------------
__global__ __launch_bounds__(256) void fill_kernel(
    const int* __restrict__ ei, const int* __restrict__ et, const float* __restrict__ ew,
    int* __restrict__ deg, int2* __restrict__ csr, int* __restrict__ ovfcnt,
    int* __restrict__ ovflist, int nE, int cap) {
    int e = blockIdx.x * blockDim.x + threadIdx.x;
    if (e >= nE) return;
    int dst = ei[nE + e];
    int pos = atomicAdd(deg + dst, 1);
    if (pos < cap) {
        int src = ei[e];
        int t = et[e];
        csr[(size_t)dst * cap + pos] = make_int2(src | (t << 20), __float_as_int(ew[e]));
    } else {
        int o = atomicAdd(ovfcnt, 1);
        ovflist[o] = e;
    }
}

// ---------------- fused gather + MFMA GEMM ----------------
// Block: 32 nodes, 512 threads (8 waves). LDS: A[32][64 chunks of 16B] (chunk^=(row&15) low-4
// XOR swizzle) @0 (32KB); B dbuf 2x8KB @32768; s[32][3] f32 @49152. Total 49536 -> 3 blocks/CU.
// Phase 1: each wave gathers 4 nodes (16 lanes/node) from f32 x, accumulates agg in regs,
// converts to bf16, writes A-tile to LDS (x part inline-converted too). Phase 2: 16 K-steps,
// B staged via global_load_lds from L2-hot bfrag, 2 MFMA/step/wave, fused bias+s+gelu epilogue.
__global__ __launch_bounds__(512, 6) void fused_gemm_kernel(
    const float* __restrict__ x, const int2* __restrict__ csr, const int* __restrict__ deg,
    const unsigned short* __restrict__ bfrag, const float* __restrict__ biasb,
    const int* __restrict__ ei, const int* __restrict__ et, const float* __restrict__ ew,
    const int* __restrict__ ovfc, const int* __restrict__ ovfl,
    float* __restrict__ out, int nN, int nE, int cap) {
    __shared__ unsigned char lds[49536];
    float* sL = (float*)(lds + 49152);
    int t = threadIdx.x;
    int w = t >> 6;
    int lane = t & 63;
    int gl = lane & 15;
    int gbase = lane & 48;
    int row0 = blockIdx.x * TM;

#define BSTAGE(buf, st_) do {                                                                     \
        const unsigned short* gsrc = bfrag + (size_t)(st_) * 4096 + w * 512 + lane * 8;           \
        unsigned char* ldst = lds + 32768 + (buf) * 8192 + w * 1024;                              \
        __builtin_amdgcn_global_load_lds((const __attribute__((address_space(1))) void*)gsrc,     \
                                         (__attribute__((address_space(3))) void*)ldst, 16, 0, 0);\
    } while (0)

    BSTAGE(0, 0);   // overlaps with the whole gather phase

    // ---------- gather phase: wave w owns nodes row0 + w*4 .. +3 ----------
    int lrow = w * 4 + (lane >> 4);
    int node = row0 + lrow;
    int nclamp = (node < nN) ? node : (nN - 1);
    int dg = (node < nN) ? deg[nclamp] : 0;
    if (dg > cap) dg = cap;
    const int2* c = csr + (size_t)nclamp * cap;
    int2 mA = (gl < dg) ? c[gl] : make_int2(0, 0);
    int2 mB = (gl + 16 < dg) ? c[gl + 16] : make_int2(0, 0);

    float ac0[8], ac1[8], ac2[8];
#pragma unroll
    for (int j = 0; j < 8; ++j) { ac0[j] = 0.f; ac1[j] = 0.f; ac2[j] = 0.f; }
    float sw0 = 0.f, sw1 = 0.f, sw2 = 0.f;

    for (int i = 0; i < dg; i += 2) {
        int slA = gbase + (i & 15);
        int exA = __shfl((i < 16) ? mA.x : mB.x, slA);
        int ewA = __shfl((i < 16) ? mA.y : mB.y, slA);
        int srcA = exA & 0xFFFFF;
        if (srcA >= nN) srcA = 0;
        float wA = __int_as_float(ewA);
        int tA = (exA >> 20) & 3;
        bool actB = (i + 1 < dg);
        int slB = gbase + ((i + 1) & 15);
        int exB = __shfl((i + 1 < 16) ? mA.x : mB.x, slB);
        int ewB = __shfl((i + 1 < 16) ? mA.y : mB.y, slB);
        int srcB = exB & 0xFFFFF;
        if (!actB || srcB >= nN) srcB = 0;
        float wB = actB ? __int_as_float(ewB) : 0.f;
        int tB = (exB >> 20) & 3;

        const float* xsA = x + (size_t)srcA * D + gl * 8;
        const float* xsB = x + (size_t)srcB * D + gl * 8;
        float4 a0 = *(const float4*)(xsA);
        float4 a1 = *(const float4*)(xsA + 4);
        float4 b0 = *(const float4*)(xsB);
        float4 b1 = *(const float4*)(xsB + 4);

        float wA0 = (tA == 0) ? wA : 0.f;
        float wA1 = (tA == 1) ? wA : 0.f;
        float wA2 = (tA == 2) ? wA : 0.f;
        float wB0 = (tB == 0) ? wB : 0.f;
        float wB1 = (tB == 1) ? wB : 0.f;
        float wB2 = (tB == 2) ? wB : 0.f;
        sw0 += wA0 + wB0; sw1 += wA1 + wB1; sw2 += wA2 + wB2;

#define ACC4(v, j0, wt0, wt1, wt2)                                         \
        ac0[j0+0] = fmaf(wt0, v.x, ac0[j0+0]); ac0[j0+1] = fmaf(wt0, v.y, ac0[j0+1]); \
        ac0[j0+2] = fmaf(wt0, v.z, ac0[j0+2]); ac0[j0+3] = fmaf(wt0, v.w, ac0[j0+3]); \
        ac1[j0+0] = fmaf(wt1, v.x, ac1[j0+0]); ac1[j0+1] = fmaf(wt1, v.y, ac1[j0+1]); \
        ac1[j0+2] = fmaf(wt1, v.z, ac1[j0+2]); ac1[j0+3] = fmaf(wt1, v.w, ac1[j0+3]); \
        ac2[j0+0] = fmaf(wt2, v.x, ac2[j0+0]); ac2[j0+1] = fmaf(wt2, v.y, ac2[j0+1]); \
        ac2[j0+2] = fmaf(wt2, v.z, ac2[j0+2]); ac2[j0+3] = fmaf(wt2, v.w, ac2[j0+3]);
        ACC4(a0, 0, wA0, wA1, wA2)
        ACC4(a1, 4, wA0, wA1, wA2)
        ACC4(b0, 0, wB0, wB1, wB2)
        ACC4(b1, 4, wB0, wB1, wB2)
#undef ACC4
    }

    // write A tile: own x (cols 0..127) + 3 agg rows, chunk-swizzled
    {
        int swz = lrow & 15;
        const float* xo = x + (size_t)nclamp * D + gl * 8;
        float4 v0 = *(const float4*)(xo);
        float4 v1 = *(const float4*)(xo + 4);
        uint4 o;
        o.x = (unsigned int)f2bf(v0.x) | ((unsigned int)f2bf(v0.y) << 16);
        o.y = (unsigned int)f2bf(v0.z) | ((unsigned int)f2bf(v0.w) << 16);
        o.z = (unsigned int)f2bf(v1.x) | ((unsigned int)f2bf(v1.y) << 16);
        o.w = (unsigned int)f2bf(v1.z) | ((unsigned int)f2bf(v1.w) << 16);
        *(uint4*)(lds + lrow * 1024 + ((gl ^ swz) << 4)) = o;
#define PACKST(arr, tt)                                                                \
        o.x = (unsigned int)f2bf(arr[0]) | ((unsigned int)f2bf(arr[1]) << 16);         \
        o.y = (unsigned int)f2bf(arr[2]) | ((unsigned int)f2bf(arr[3]) << 16);         \
        o.z = (unsigned int)f2bf(arr[4]) | ((unsigned int)f2bf(arr[5]) << 16);         \
        o.w = (unsigned int)f2bf(arr[6]) | ((unsigned int)f2bf(arr[7]) << 16);         \
        *(uint4*)(lds + lrow * 1024 + 256 + (tt) * 256 + ((gl ^ swz) << 4)) = o;
        PACKST(ac0, 0)
        PACKST(ac1, 1)
        PACKST(ac2, 2)
#undef PACKST
        if (gl < 3) {
            float sv = (gl == 0) ? sw0 : ((gl == 1) ? sw1 : sw2);
            sL[lrow * NT + gl] = sv;
        }
    }
    __syncthreads();

    // ---------- overflow patch (cnt == 0 in practice; correct for any data) ----------
    int cnt = *ovfc;
    if (cnt > 0) {
        if (w == 0 && lane < 16) {
            for (int i = 0; i < cnt; ++i) {
                int e = ovfl[i];
                int dst = ei[nE + e];
                if (dst >= row0 && dst < row0 + TM && dst < nN) {
                    int tt = et[e];
                    float wt = ew[e];
                    int src = ei[e];
                    int lr = dst - row0;
                    int swz = lr & 15;
                    uint4* p = (uint4*)(lds + lr * 1024 + 256 + tt * 256 + ((lane ^ swz) << 4));
                    uint4 cu = *p;
                    const float* xs = x + (size_t)src * D + lane * 8;
                    float4 q0 = *(const float4*)(xs);
                    float4 q1 = *(const float4*)(xs + 4);
                    float f[8];
                    f[0] = bf2f(cu.x & 0xFFFF) + wt * q0.x; f[1] = bf2f(cu.x >> 16) + wt * q0.y;
                    f[2] = bf2f(cu.y & 0xFFFF) + wt * q0.z; f[3] = bf2f(cu.y >> 16) + wt * q0.w;
                    f[4] = bf2f(cu.z & 0xFFFF) + wt * q1.x; f[5] = bf2f(cu.z >> 16) + wt * q1.y;
                    f[6] = bf2f(cu.w & 0xFFFF) + wt * q1.z; f[7] = bf2f(cu.w >> 16) + wt * q1.w;
                    cu.x = (unsigned int)f2bf(f[0]) | ((unsigned int)f2bf(f[1]) << 16);
                    cu.y = (unsigned int)f2bf(f[2]) | ((unsigned int)f2bf(f[3]) << 16);
                    cu.z = (unsigned int)f2bf(f[4]) | ((unsigned int)f2bf(f[5]) << 16);
                    cu.w = (unsigned int)f2bf(f[6]) | ((unsigned int)f2bf(f[7]) << 16);
                    *p = cu;
                    if (lane == 0) sL[lr * NT + tt] += wt;
                }
            }
        }
        __syncthreads();
    }

    // ---------- GEMM phase: 16 K-steps, wave w covers cols w*16..+15 ----------
    int ll = lane & 15;
    int ck = lane >> 4;
    f32x4 acc0 = (f32x4){0.f, 0.f, 0.f, 0.f};
    f32x4 acc1 = (f32x4){0.f, 0.f, 0.f, 0.f};
#pragma unroll 2
    for (int st = 0; st < 16; ++st) {
        int cur = st & 1;
        if (st < 15) BSTAGE(cur ^ 1, st + 1);
        int cc = st * 4 + ck;
        int phys = (cc & 48) | ((cc & 15) ^ ll);
        bf16x8 a0 = *(const bf16x8*)(lds + ll * 1024 + (phys << 4));
        bf16x8 a1 = *(const bf16x8*)(lds + (16 + ll) * 1024 + (phys << 4));
        bf16x8 b = *(const bf16x8*)(lds + 32768 + cur * 8192 + ((w * 64 + lane) << 4));
        acc0 = __builtin_amdgcn_mfma_f32_16x16x32_bf16(a0, b, acc0, 0, 0, 0);
        acc1 = __builtin_amdgcn_mfma_f32_16x16x32_bf16(a1, b, acc1, 0, 0, 0);
        __syncthreads();
    }
#undef BSTAGE

    // ---------- epilogue ----------
    int colb = w * 16 + ll;
    float bb0 = biasb[colb], bb1 = biasb[D + colb], bb2 = biasb[2 * D + colb], bs4 = biasb[3 * D + colb];
    const float kInvSqrt2 = 0.70710678118654752440f;
#pragma unroll
    for (int fr = 0; fr < 2; ++fr) {
        f32x4 A = fr ? acc1 : acc0;
#pragma unroll
        for (int reg = 0; reg < 4; ++reg) {
            int lr = fr * 16 + ck * 4 + reg;
            long row = (long)row0 + lr;
            if (row >= nN) continue;
            float s0 = sL[lr * NT + 0];
            float s1 = sL[lr * NT + 1];
            float s2 = sL[lr * NT + 2];
            float v = A[reg] + bs4 + s0 * bb0 + s1 * bb1 + s2 * bb2;
            v = 0.5f * v * (1.f + erff(v * kInvSqrt2));
            out[row * D + colb] = v;
        }
    }
}

// ================= FALLBACK PATH (small ws): f32 atomic scatter + f32 GEMM =================
__global__ __launch_bounds__(256) void scatterA_kernel(
    const float* __restrict__ x, const int* __restrict__ ei,
    const int* __restrict__ et, const float* __restrict__ ew,
    float* __restrict__ agg, float* __restrict__ s, int nE) {
    int gtid = blockIdx.x * blockDim.x + threadIdx.x;
    int wave = gtid >> 6;
    int lane = threadIdx.x & 63;
    int nw = (gridDim.x * blockDim.x) >> 6;
    for (int e = wave; e < nE; e += nw) {
        int src = ei[e];
        int dst = ei[nE + e];
        int t = et[e];
        float w = ew[e];
        float2 xv = *(const float2*)(x + (size_t)src * D + lane * 2);
        float* p = agg + (size_t)dst * (NT * D) + t * D + lane * 2;
        unsafeAtomicAdd(p, w * xv.x);
        unsafeAtomicAdd(p + 1, w * xv.y);
        if (lane == 0) unsafeAtomicAdd(s + (size_t)dst * NT + t, w);
    }
}

#define BM 64
#define BK 32
__global__ __launch_bounds__(256) void gemm_gelu_kernel(
    const float* __restrict__ x, const float* __restrict__ agg,
    const float* __restrict__ s, const float* __restrict__ wcat,
    const float* __restrict__ biasb, float* __restrict__ out, int nNodes) {
    __shared__ float As[BK][BM + 1];
    __shared__ float Bs[BK][D];

    int tx = threadIdx.x;
    int row0 = blockIdx.x * BM;
    int cg = tx & 31;
    int rg = tx >> 5;
    int lr = tx >> 3;
    int lc = (tx & 7) * 4;

    float acc[8][4];
#pragma unroll
    for (int i = 0; i < 8; ++i)
#pragma unroll
        for (int j = 0; j < 4; ++j) acc[i][j] = 0.f;

    for (int k0 = 0; k0 < KTOT; k0 += BK) {
        const float* srcBase;
        int strideA, koff;
        if (k0 < D) { srcBase = x; strideA = D; koff = k0; }
        else        { srcBase = agg; strideA = NT * D; koff = k0 - D; }
#pragma unroll
        for (int h = 0; h < 2; ++h) {
            int r = lr + h * 32;
            int node = row0 + r;
            if (node >= nNodes) node = nNodes - 1;
            float4 v = *(const float4*)(srcBase + (size_t)node * strideA + koff + lc);
            As[lc + 0][r] = v.x; As[lc + 1][r] = v.y;
            As[lc + 2][r] = v.z; As[lc + 3][r] = v.w;
        }
        {
            int br = tx >> 5;
            int bc = (tx & 31) * 4;
#pragma unroll
            for (int h = 0; h < 4; ++h) {
                int r = br + h * 8;
                *(float4*)(&Bs[r][bc]) = *(const float4*)(wcat + (size_t)(k0 + r) * D + bc);
            }
        }
        __syncthreads();
#pragma unroll
        for (int kk = 0; kk < BK; ++kk) {
            float4 b = *(const float4*)(&Bs[kk][cg * 4]);
            float a[8];
            *(float4*)(a)     = *(const float4*)(&As[kk][rg * 8]);
            *(float4*)(a + 4) = *(const float4*)(&As[kk][rg * 8 + 4]);
#pragma unroll
            for (int i = 0; i < 8; ++i) {
                acc[i][0] = fmaf(a[i], b.x, acc[i][0]);
                acc[i][1] = fmaf(a[i], b.y, acc[i][1]);
                acc[i][2] = fmaf(a[i], b.z, acc[i][2]);
                acc[i][3] = fmaf(a[i], b.w, acc[i][3]);
            }
        }
        __syncthreads();
    }

    int jc = cg * 4;
    float4 bb0 = *(const float4*)(biasb + 0 * D + jc);
    float4 bb1 = *(const float4*)(biasb + 1 * D + jc);
    float4 bb2 = *(const float4*)(biasb + 2 * D + jc);
    float4 bsv = *(const float4*)(biasb + NT * D + jc);
#pragma unroll
    for (int i = 0; i < 8; ++i) {
        int node = row0 + rg * 8 + i;
        if (node >= nNodes) break;
        float s0 = s[(size_t)node * NT + 0];
        float s1 = s[(size_t)node * NT + 1];
        float s2 = s[(size_t)node * NT + 2];
        float4 r;
        r.x = acc[i][0] + bsv.x + s0 * bb0.x + s1 * bb1.x + s2 * bb2.x;
        r.y = acc[i][1] + bsv.y + s0 * bb0.y + s1 * bb1.y + s2 * bb2.y;
        r.z = acc[i][2] + bsv.z + s0 * bb0.z + s1 * bb1.z + s2 * bb2.z;
        r.w = acc[i][3] + bsv.w + s0 * bb0.w + s1 * bb1.w + s2 * bb2.w;
        const float kInvSqrt2 = 0.70710678118654752440f;
        r.x = 0.5f * r.x * (1.f + erff(r.x * kInvSqrt2));
        r.y = 0.5f * r.y * (1.f + erff(r.y * kInvSqrt2));
        r.z = 0.5f * r.z * (1.f + erff(r.z * kInvSqrt2));
        r.w = 0.5f * r.w * (1.f + erff(r.w * kInvSqrt2));
        *(float4*)(out + (size_t)node * D + jc) = r;
    }
}

// ================= PATH C: zero-workspace fallback =================
__global__ __launch_bounds__(256) void selfmv_kernel(
    const float* __restrict__ x, const float* __restrict__ Ws,
    const float* __restrict__ bs, const float* __restrict__ attn,
    float* __restrict__ out, int nN) {
    float a0 = attn[0], a1 = attn[1], a2 = attn[2], a3 = attn[3];
    float m = fmaxf(fmaxf(a0, a1), fmaxf(a2, a3));
    float e3 = expf(a3 - m);
    float inv = 1.f / (expf(a0 - m) + expf(a1 - m) + expf(a2 - m) + e3);
    float at3 = e3 * inv;
    int wave = (blockIdx.x * blockDim.x + threadIdx.x) >> 6;
    int lane = threadIdx.x & 63;
    int nw = (gridDim.x * blockDim.x) >> 6;
    for (int n = wave; n < nN; n += nw) {
        float2 xr = *(const float2*)(x + (size_t)n * D + lane * 2);
        float acc0 = 0.f, acc1 = 0.f;
#pragma unroll
        for (int k = 0; k < D; ++k) {
            float xv = __shfl((k & 1) ? xr.y : xr.x, k >> 1);
            float2 wv = *(const float2*)(Ws + (size_t)k * D + lane * 2);
            acc0 = fmaf(xv, wv.x, acc0);
            acc1 = fmaf(xv, wv.y, acc1);
        }
        float2 r;
        r.x = at3 * (acc0 + bs[lane * 2]);
        r.y = at3 * (acc1 + bs[lane * 2 + 1]);
        *(float2*)(out + (size_t)n * D + lane * 2) = r;
    }
}

__global__ __launch_bounds__(256) void edgemv_kernel(
    const float* __restrict__ x, const int* __restrict__ ei,
    const int* __restrict__ et, const float* __restrict__ ew,
    const float* __restrict__ We, const float* __restrict__ be,
    const float* __restrict__ attn, float* __restrict__ out, int nE) {
    float a0 = attn[0], a1 = attn[1], a2 = attn[2], a3 = attn[3];
    float m = fmaxf(fmaxf(a0, a1), fmaxf(a2, a3));
    float e0 = expf(a0 - m), e1 = expf(a1 - m), e2 = expf(a2 - m), e3 = expf(a3 - m);
    float inv = 1.f / (e0 + e1 + e2 + e3);
    float at[NT] = {e0 * inv, e1 * inv, e2 * inv};
    int wave = (blockIdx.x * blockDim.x + threadIdx.x) >> 6;
    int lane = threadIdx.x & 63;
    int nw = (gridDim.x * blockDim.x) >> 6;
    for (int e = wave; e < nE; e += nw) {
        int src = ei[e];
        int dst = ei[nE + e];
        int t = et[e];
        float sc = ew[e] * at[t];
        const float* W = We + (size_t)t * D * D;
        float2 xr = *(const float2*)(x + (size_t)src * D + lane * 2);
        float acc0 = 0.f, acc1 = 0.f;
#pragma unroll
        for (int k = 0; k < D; ++k) {
            float xv = __shfl((k & 1) ? xr.y : xr.x, k >> 1);
            float2 wv = *(const float2*)(W + (size_t)k * D + lane * 2);
            acc0 = fmaf(xv, wv.x, acc0);
            acc1 = fmaf(xv, wv.y, acc1);
        }
        float* p = out + (size_t)dst * D + lane * 2;
        unsafeAtomicAdd(p,     sc * (acc0 + be[(size_t)t * D + lane * 2]));
        unsafeAtomicAdd(p + 1, sc * (acc1 + be[(size_t)t * D + lane * 2 + 1]));
    }
}

__global__ void gelu_kernel(float* __restrict__ p, long long n4) {
    long long i = (long long)blockIdx.x * blockDim.x + threadIdx.x;
    long long stride = (long long)gridDim.x * blockDim.x;
    const float kInvSqrt2 = 0.70710678118654752440f;
    for (; i < n4; i += stride) {
        float4 r = ((float4*)p)[i];
        r.x = 0.5f * r.x * (1.f + erff(r.x * kInvSqrt2));
        r.y = 0.5f * r.y * (1.f + erff(r.y * kInvSqrt2));
        r.z = 0.5f * r.z * (1.f + erff(r.z * kInvSqrt2));
        r.w = 0.5f * r.w * (1.f + erff(r.w * kInvSqrt2));
        ((float4*)p)[i] = r;
    }
}

extern "C" void kernel_launch(void* const* d_in, const int* in_sizes, int n_in,
                              void* d_out, int out_size, void* d_ws, size_t ws_size,
                              hipStream_t stream) {
    const float* x = (const float*)d_in[0];
    const int* ei = (const int*)d_in[1];      // int64 in reference -> int32 here
    const int* et = (const int*)d_in[2];
    const float* ew = (const float*)d_in[3];
    const float* W_edge = (const float*)d_in[4];
    const float* b_edge = (const float*)d_in[5];
    const float* W_self = (const float*)d_in[6];
    const float* b_self = (const float*)d_in[7];
    const float* attention = (const float*)d_in[8];
    float* out = (float*)d_out;

    const int nN = in_sizes[0] / D;   // 100000
    const int nE = in_sizes[2];       // 600000
    const int cap = 32;

    // ---- fused path workspace ----
    // wcat (f32, fallback-shared) | biasb | bfrag | deg+ovfc | ovflist | csr
    size_t needFused = (size_t)(KTOT * D + KTOT) * 4 + 131072
                     + 4 * ((size_t)nN + 2 + (size_t)nE) + 8ull * nN * cap;

    if (ws_size >= needFused && nN < (1 << 20)) {
        float* wcat = (float*)d_ws;
        float* biasb = wcat + (size_t)KTOT * D;
        unsigned short* bfrag = (unsigned short*)(biasb + KTOT);   // 65536 shorts
        int* deg = (int*)(bfrag + 65536);
        int* ovfc = deg + nN;
        int* ovfl = ovfc + 2;
        int2* csr = (int2*)(ovfl + nE);

        hipLaunchKernelGGL(prep_kernel, dim3(64), dim3(256), 0, stream,
                           W_edge, b_edge, W_self, b_self, attention, wcat, biasb, bfrag,
                           deg, nN + 2);
        hipLaunchKernelGGL(fill_kernel, dim3((nE + 255) / 256), dim3(256), 0, stream,
                           ei, et, ew, deg, csr, ovfc, ovfl, nE, cap);
        hipLaunchKernelGGL(fused_gemm_kernel, dim3((nN + TM - 1) / TM), dim3(512), 0, stream,
                           x, csr, deg, bfrag, biasb, ei, et, ew, ovfc, ovfl, out, nN, nE, cap);
        return;
    }

    const size_t baseFloats = (size_t)nN * NT * D + (size_t)nN * NT + (size_t)KTOT * D + KTOT;
    if (ws_size >= baseFloats * 4) {
        float* agg = (float*)d_ws;
        float* sW = agg + (size_t)nN * NT * D;
        float* wcat = sW + (size_t)nN * NT;
        float* biasb = wcat + (size_t)KTOT * D;
        long long zeroFloats = (long long)nN * (NT * D + NT);
        hipLaunchKernelGGL(zero_kernel, dim3(2048), dim3(256), 0, stream, agg, (zeroFloats + 3) / 4);
        hipLaunchKernelGGL(prep_kernel, dim3(64), dim3(256), 0, stream,
                           W_edge, b_edge, W_self, b_self, attention, wcat, biasb,
                           (unsigned short*)nullptr, (int*)nullptr, 0);
        hipLaunchKernelGGL(scatterA_kernel, dim3(2048), dim3(256), 0, stream,
                           x, ei, et, ew, agg, sW, nE);
        hipLaunchKernelGGL(gemm_gelu_kernel, dim3((nN + BM - 1) / BM), dim3(256), 0, stream,
                           x, agg, sW, wcat, biasb, out, nN);
    } else {
        hipLaunchKernelGGL(selfmv_kernel, dim3(2048), dim3(256), 0, stream,
                           x, W_self, b_self, attention, out, nN);
        hipLaunchKernelGGL(edgemv_kernel, dim3(2048), dim3(256), 0, stream,
                           x, ei, et, ew, W_edge, b_edge, attention, out, nE);
        hipLaunchKernelGGL(gelu_kernel, dim3(2048), dim3(256), 0, stream,
                           out, (long long)nN * D / 4);
    }
}